// Round 2
// baseline (756.819 us; speedup 1.0000x reference)
//
#include <hip/hip_runtime.h>
#include <stdint.h>

typedef float f32x4 __attribute__((ext_vector_type(4)));
typedef short s16x8 __attribute__((ext_vector_type(8)));
typedef unsigned short u16;

// ---------- helpers ----------
__device__ __forceinline__ u16 f2bf(float f) {
  union { float f; uint32_t u; } c; c.f = f;
  uint32_t u = c.u;
  u = (u + 0x7fffu + ((u >> 16) & 1u)) >> 16;   // RNE
  return (u16)u;
}

__device__ __forceinline__ u16 f2bf_fast(float f) {  // round-half-up, 2 VALU
  union { float f; uint32_t u; } c; c.f = f;
  return (u16)((c.u + 0x8000u) >> 16);
}

__device__ __forceinline__ void gload16(const void* g, void* lds) {
  __builtin_amdgcn_global_load_lds(
      (const __attribute__((address_space(1))) void*)g,
      (__attribute__((address_space(3))) void*)lds, 16, 0, 0);
}

__device__ __forceinline__ f32x4 mfma16(s16x8 a, s16x8 b, f32x4 c) {
  return __builtin_amdgcn_mfma_f32_16x16x32_bf16(a, b, c, 0, 0, 0);
}

// swizzled offset into an unpadded [rows][64] u16 tile: element block (row, c8)
__device__ __forceinline__ int swz(int row, int c8) {
  return row * 64 + ((c8 ^ (row & 7)) << 3);
}

// ---------- small prep kernels ----------
__global__ void cvt_bf16(const float* __restrict__ in, u16* __restrict__ out, size_t n) {
  size_t i = ((size_t)blockIdx.x * blockDim.x + threadIdx.x) * 4;
  if (i < n) {
    float4 v = *(const float4*)&in[i];
    u16 o0 = f2bf(v.x), o1 = f2bf(v.y), o2 = f2bf(v.z), o3 = f2bf(v.w);
    uint2 packed;
    packed.x = (uint32_t)o0 | ((uint32_t)o1 << 16);
    packed.y = (uint32_t)o2 | ((uint32_t)o3 << 16);
    *(uint2*)&out[i] = packed;
  }
}

// tiled transpose: in [rows][cols] fp32 -> out [cols][rows] bf16. grid (cols/64, rows/64)
__global__ void transpose_cvt(const float* __restrict__ in, u16* __restrict__ out,
                              int rows, int cols) {
  __shared__ float tile[64][65];
  const int c0 = blockIdx.x * 64, r0 = blockIdx.y * 64;
  const int tr = threadIdx.x >> 6, tc = threadIdx.x & 63;
#pragma unroll
  for (int i = 0; i < 16; i++) {
    int r = i * 4 + tr;
    tile[r][tc] = in[(size_t)(r0 + r) * cols + c0 + tc];
  }
  __syncthreads();
#pragma unroll
  for (int i = 0; i < 16; i++) {
    int oc = i * 4 + tr;                 // column of `in`
    out[(size_t)(c0 + oc) * rows + r0 + tc] = f2bf(tile[tc][oc]);
  }
}

__global__ void rope_tables_kernel(float* __restrict__ cosT, float* __restrict__ sinT) {
  int n = blockIdx.x;        // 0..1023
  int d = threadIdx.x;       // 0..63
  int ph = n >> 5, pw = n & 31;
  int pos = (d < 32) ? ph : pw;
  int fi = d & 15;
  float freq = powf(10000.f, -(float)fi / 16.f);
  float ang = (float)pos * freq;
  cosT[n * 64 + d] = cosf(ang);
  sinT[n * 64 + d] = sinf(ang);
}

// ============================================================================
// 256x256 8-phase GEMM mainloop (T2 swizzle + T3/T4 counted vmcnt + T5 setprio)
// See R0 notes: 512 thr / 8 waves (2M x 4N), BK=64, LDS 128KB dbuf.
// ============================================================================

#define PH_MID \
  __builtin_amdgcn_sched_barrier(0); \
  __builtin_amdgcn_s_barrier(); \
  asm volatile("s_waitcnt lgkmcnt(0)" ::: "memory"); \
  __builtin_amdgcn_sched_barrier(0); \
  __builtin_amdgcn_s_setprio(1);

#define PH_END \
  __builtin_amdgcn_s_setprio(0); \
  __builtin_amdgcn_sched_barrier(0); \
  __builtin_amdgcn_s_barrier(); \
  __builtin_amdgcn_sched_barrier(0);

#define STAGE(ldsoff, g) do { \
    gload16((g) + (size_t)(w8 + srow) * 1024 + sc8 * 8,       &lds[(ldsoff) + w8 * 64]); \
    gload16((g) + (size_t)(w8 + srow + 64) * 1024 + sc8 * 8,  &lds[(ldsoff) + (w8 + 64) * 64]); \
  } while (0)

#define RD_A(dst, BUF, mh) \
  _Pragma("unroll") \
  for (int mi = 0; mi < 4; mi++) { \
    dst[mi][0] = *(const s16x8*)&lds[(BUF) * 32768 + arow0 + ((mh) * 64 + mi * 16) * 64 + swz0]; \
    dst[mi][1] = *(const s16x8*)&lds[(BUF) * 32768 + arow0 + ((mh) * 64 + mi * 16) * 64 + swz1]; \
  }

#define RD_B(dst, BUF, nh) \
  _Pragma("unroll") \
  for (int ni = 0; ni < 2; ni++) { \
    dst[ni][0] = *(const s16x8*)&lds[(BUF) * 32768 + 16384 + brow0 + ((nh) * 32 + ni * 16) * 64 + swz0]; \
    dst[ni][1] = *(const s16x8*)&lds[(BUF) * 32768 + 16384 + brow0 + ((nh) * 32 + ni * 16) * 64 + swz1]; \
  }

#define MFMA_QUAD(af, bfr, mh, nh) \
  _Pragma("unroll") \
  for (int mi = 0; mi < 4; mi++) \
    _Pragma("unroll") \
    for (int ni = 0; ni < 2; ni++) { \
      acc[(mh) * 4 + mi][(nh) * 2 + ni] = mfma16(af[mi][0], bfr[ni][0], acc[(mh) * 4 + mi][(nh) * 2 + ni]); \
      acc[(mh) * 4 + mi][(nh) * 2 + ni] = mfma16(af[mi][1], bfr[ni][1], acc[(mh) * 4 + mi][(nh) * 2 + ni]); \
    }

// MODE: 0 = steady; 1 = kt==14 (prefetch A only, vmcnt(0)); 2 = kt==15 (no prefetch)
#define KTILE(BUF, KT, MODE) do { \
    s16x8 a0f[4][2], a1f[4][2], b0f[2][2], b1f[2][2]; \
    /* P1 */ \
    RD_A(a0f, BUF, 0); \
    RD_B(b0f, BUF, 0); \
    if ((MODE) < 2) STAGE((1 - (BUF)) * 32768, Ag + (size_t)((KT) + 1) * 64); \
    PH_MID; MFMA_QUAD(a0f, b0f, 0, 0); PH_END; \
    /* P2 */ \
    RD_B(b1f, BUF, 1); \
    if ((MODE) < 2) STAGE((1 - (BUF)) * 32768 + 8192, Ag + (size_t)128 * 1024 + ((KT) + 1) * 64); \
    PH_MID; MFMA_QUAD(a0f, b1f, 0, 1); PH_END; \
    /* P3 */ \
    RD_A(a1f, BUF, 1); \
    if ((MODE) == 0) STAGE((BUF) * 32768 + 16384, Bg + (size_t)((KT) + 2) * 64); \
    PH_MID; MFMA_QUAD(a1f, b1f, 1, 1); PH_END; \
    /* P4 */ \
    if ((MODE) == 0) STAGE((BUF) * 32768 + 16384 + 8192, Bg + (size_t)128 * 1024 + ((KT) + 2) * 64); \
    PH_MID; MFMA_QUAD(a1f, b0f, 1, 0); \
    __builtin_amdgcn_s_setprio(0); \
    if ((MODE) == 0) asm volatile("s_waitcnt vmcnt(4)" ::: "memory"); \
    if ((MODE) == 1) asm volatile("s_waitcnt vmcnt(0)" ::: "memory"); \
    __builtin_amdgcn_sched_barrier(0); \
    __builtin_amdgcn_s_barrier(); \
    __builtin_amdgcn_sched_barrier(0); \
  } while (0)

__device__ __forceinline__ void gemm_mainloop_8ph(
    const u16* __restrict__ Ag, const u16* __restrict__ Bg,
    u16* lds, f32x4 (&acc)[8][4])
{
  const int t = threadIdx.x;
  const int l = t & 63, w = t >> 6;
  const int wm = w & 1, wn = w >> 1;
  const int lrow = l & 15, lg = l >> 4;
  const int srow = l >> 3, sc8 = (l & 7) ^ srow;   // pre-swizzled global chunk
  const int w8 = w * 8;
  const int swz0 = ((0 + lg) ^ (lrow & 7)) << 3;   // kh = 0 (K 0..31)
  const int swz1 = ((4 + lg) ^ (lrow & 7)) << 3;   // kh = 1 (K 32..63)
  const int arow0 = (wm * 128 + lrow) * 64;
  const int brow0 = (wn * 64 + lrow) * 64;

  STAGE(0,                 Ag);
  STAGE(8192,              Ag + (size_t)128 * 1024);
  STAGE(16384,             Bg);
  STAGE(16384 + 8192,      Bg + (size_t)128 * 1024);
  STAGE(32768 + 16384,          Bg + 64);
  STAGE(32768 + 16384 + 8192,   Bg + (size_t)128 * 1024 + 64);
  asm volatile("s_waitcnt vmcnt(4)" ::: "memory");   // kt0 complete; {B0,B1}_1 in flight
  __builtin_amdgcn_sched_barrier(0);
  __builtin_amdgcn_s_barrier();
  __builtin_amdgcn_sched_barrier(0);

#pragma unroll 1
  for (int kt = 0; kt < 14; kt += 2) {
    KTILE(0, kt, 0);
    KTILE(1, kt + 1, 0);
  }
  KTILE(0, 14, 1);
  KTILE(1, 15, 2);
}

// ---------- QKV GEMM + bias + RMSNorm(q,k) + RoPE + q-scale ----------
// q/k written [B*H][N][64]; v written TRANSPOSED per head: [B*H][64][N]
__global__ __launch_bounds__(512, 2) void gemm_qkv(
    const u16* __restrict__ A,   // x bf16 [32768][1024]
    const u16* __restrict__ Bt,  // qkv_w^T bf16 [3072][1024]
    const float* __restrict__ bias,
    const float* __restrict__ qgam, const float* __restrict__ kgam,
    const float* __restrict__ cosT, const float* __restrict__ sinT,
    u16* __restrict__ qb, u16* __restrict__ kb, u16* __restrict__ vb)
{
  __shared__ u16 lds[65536];   // 128 KB
  // XCD-aware bijective swizzle: nwg = 1536 = 8 * 192
  const int bid = blockIdx.x;
  const int sb = (bid & 7) * 192 + (bid >> 3);
  const int bm = sb / 12, bn = sb % 12;

  const f32x4 fzero = {0.f, 0.f, 0.f, 0.f};
  f32x4 acc[8][4];
#pragma unroll
  for (int i = 0; i < 8; i++)
#pragma unroll
    for (int j = 0; j < 4; j++) acc[i][j] = fzero;

  gemm_mainloop_8ph(A + (size_t)bm * 256 * 1024, Bt + (size_t)bn * 256 * 1024, lds, acc);

  const int t = threadIdx.x, l = t & 63, w = t >> 6;
  const int wm = w & 1, wn = w >> 1, lrow = l & 15, lg = l >> 4;
  const int colb = bn * 256 + wn * 64;       // 64-aligned -> single head per wave
  const int s = colb >> 10;                  // 0=q 1=k 2=v
  const int h = (colb & 1023) >> 6;

  float biasv[4];
#pragma unroll
  for (int nt = 0; nt < 4; nt++) biasv[nt] = bias[colb + nt * 16 + lrow];

  if (s < 2) {
    u16* dst = (s == 0) ? qb : kb;
    const float mul = (s == 0) ? 0.18033688011112042f : 1.0f;  // 0.125*log2(e) folded into q
    const float* gamma = (s == 0) ? qgam : kgam;
    float g[4];
#pragma unroll
    for (int nt = 0; nt < 4; nt++) g[nt] = gamma[nt * 16 + lrow] * mul;  // fold q-scale
#pragma unroll
    for (int mf = 0; mf < 8; mf++) {
#pragma unroll
      for (int r = 0; r < 4; r++) {
        const int rowg = bm * 256 + wm * 128 + mf * 16 + lg * 4 + r;
        const int b = rowg >> 10, np = rowg & 1023;
        float tmp[4]; float sq = 0.f;
#pragma unroll
        for (int nt = 0; nt < 4; nt++) {
          float v = acc[mf][nt][r] + biasv[nt];
          tmp[nt] = v; sq += v * v;
        }
#pragma unroll
        for (int off = 1; off < 16; off <<= 1) sq += __shfl_xor(sq, off);
        const float rstd = rsqrtf(sq * 0.015625f + 1e-6f);
#pragma unroll
        for (int nt = 0; nt < 4; nt++) tmp[nt] *= rstd * g[nt];
        const size_t base = (((size_t)(b * 16 + h)) * 1024 + np) * 64;
#pragma unroll
        for (int nt = 0; nt < 4; nt++) {
          const int d = nt * 16 + lrow;
          const float cv = cosT[np * 64 + d], sv = sinT[np * 64 + d];
          const float rh = (nt < 2) ? -tmp[nt + 2] : tmp[nt - 2];
          dst[base + d] = f2bf(tmp[nt] * cv + rh * sv);
        }
      }
    }
  } else {
    // V transposed: vb[(bh*64 + d)*1024 + np].
    // Old path: 128 x 2B stores at 2KB lane stride (64 lines per store) -> terrible.
    // New path: transpose through the (now-dead) mainloop LDS, wave-private 16KB
    // region as [64 d][128 np] u16 with 16B-chunk XOR swizzle, then 16 coalesced
    // dwordx4 wave-stores.
    u16* L = &lds[w * 8192];
    const int b = bm >> 2;                       // block never crosses a batch row-group
    const int np0w = (bm & 3) * 256 + wm * 128;  // wave's first np
    const size_t hb = ((size_t)(b * 16 + h)) * 64;
#pragma unroll
    for (int mf = 0; mf < 8; mf++) {
      const int c = mf * 2 + (lg >> 1);          // 16B chunk index along np (0..15)
#pragma unroll
      for (int nt = 0; nt < 4; nt++) {
        const int d = nt * 16 + lrow;            // d & 15 == lrow
        u16 p0 = f2bf(acc[mf][nt][0] + biasv[nt]);
        u16 p1 = f2bf(acc[mf][nt][1] + biasv[nt]);
        u16 p2 = f2bf(acc[mf][nt][2] + biasv[nt]);
        u16 p3 = f2bf(acc[mf][nt][3] + biasv[nt]);
        uint2 pk;
        pk.x = (uint32_t)p0 | ((uint32_t)p1 << 16);
        pk.y = (uint32_t)p2 | ((uint32_t)p3 << 16);
        *(uint2*)&L[d * 128 + ((c ^ lrow) << 3) + (lg & 1) * 4] = pk;
      }
    }
    // wave-private region: no barrier needed; compiler orders ds_write->ds_read.
#pragma unroll
    for (int i = 0; i < 16; i++) {
      const int d = i * 4 + lg >= 64 ? 0 : i * 4 + (l >> 4);  // placeholder (see below)
      (void)d;
    }
#pragma unroll
    for (int i = 0; i < 16; i++) {
      const int dq = l >> 4, jj = l & 15;
      const int d = i * 4 + dq;
      s16x8 vrow = *(const s16x8*)&L[d * 128 + ((jj ^ (d & 15)) << 3)];
      *(s16x8*)&vb[(hb + d) * 1024 + np0w + jj * 8] = vrow;
    }
  }
}

// ---------- flash attention, double-buffered K/VT ----------
// grid 512*(1024/128); block 256 = 4 waves, each wave 32 q-rows (2 m-frags).
// Q,K row-major per head [1024][64]; V transposed per head [64][1024].
// No running max: |s*scale*log2e| <= 11.5 (RMS-normed q,k), exp2 never overflows.
// Per tile: issue next K/VT gloads FIRST (latency hides under QK^T+softmax+PV),
// one __syncthreads per tile (its implicit vmcnt(0)+lgkmcnt(0) drains the stage).
__global__ __launch_bounds__(256, 2) void attn_kernel(
    const u16* __restrict__ qbuf, const u16* __restrict__ kbuf,
    const u16* __restrict__ vtbuf, u16* __restrict__ obuf)
{
  __shared__ u16 Qs[128 * 64];     // 16KB, xor-swizzled
  __shared__ u16 Ks[2][64 * 64];   // 16KB double-buffered
  __shared__ u16 VTs[2][64 * 64];  // 16KB double-buffered (rows = d, cols = k)
  __shared__ u16 Ps[128 * 64];     // 16KB
  const int bx = blockIdx.x;
  const int bh = bx >> 3, qt = bx & 7;
  const int t = threadIdx.x, l = t & 63, w = t >> 6;
  const int lrow = l & 15, lg = l >> 4;

  const u16* qg  = qbuf  + (size_t)bh * 65536 + (size_t)qt * 8192;
  const u16* kg0 = kbuf  + (size_t)bh * 65536;
  const u16* vt0 = vtbuf + (size_t)bh * 65536;

  // staging geometry: lane covers (row r0 + l>>3, swizzled chunk)
  const int srow = l >> 3;
  const int sc8  = (l & 7) ^ (srow & 7);   // global c8 this lane fetches

  // stage Q (128x64)
#pragma unroll
  for (int i = 0; i < 4; i++) {
    const int r0 = (w + i * 4) * 8;
    gload16(qg + (size_t)(r0 + srow) * 64 + sc8 * 8, &Qs[r0 * 64]);
  }
  // stage K,VT tile 0 into buffer 0
#pragma unroll
  for (int i = 0; i < 2; i++) {
    const int r0 = (w + i * 4) * 8;
    gload16(kg0 + (size_t)(r0 + srow) * 64 + sc8 * 8, &Ks[0][r0 * 64]);
    gload16(vt0 + (size_t)(r0 + srow) * 1024 + sc8 * 8, &VTs[0][r0 * 64]);
  }
  asm volatile("s_waitcnt vmcnt(0)" ::: "memory");
  __syncthreads();

  // Q frags held in regs for the whole loop
  s16x8 aq[2][2];
#pragma unroll
  for (int mt = 0; mt < 2; mt++)
#pragma unroll
    for (int kh = 0; kh < 2; kh++)
      aq[mt][kh] = *(const s16x8*)&Qs[swz(w * 32 + mt * 16 + lrow, kh * 4 + lg)];

  const f32x4 fzero = {0.f, 0.f, 0.f, 0.f};
  f32x4 o[2][4];
  float l_[2][4];
#pragma unroll
  for (int mt = 0; mt < 2; mt++) {
#pragma unroll
    for (int dt = 0; dt < 4; dt++) o[mt][dt] = fzero;
#pragma unroll
    for (int r = 0; r < 4; r++) l_[mt][r] = 0.f;
  }

#pragma unroll 2
  for (int kt = 0; kt < 16; kt++) {
    const int cur = kt & 1;
    // ---- issue next tile's stage FIRST: latency hides under this tile's compute ----
    if (kt < 15) {
      const int kb = (kt + 1) * 64;
#pragma unroll
      for (int i = 0; i < 2; i++) {
        const int r0 = (w + i * 4) * 8;
        gload16(kg0 + (size_t)(kb + r0 + srow) * 64 + sc8 * 8, &Ks[cur ^ 1][r0 * 64]);
        gload16(vt0 + (size_t)(r0 + srow) * 1024 + kb + sc8 * 8, &VTs[cur ^ 1][r0 * 64]);
      }
    }

    // ---- S = Q K^T (log2-domain scores; q carries 0.125*log2e) ----
    s16x8 bk[4][2];
#pragma unroll
    for (int nt = 0; nt < 4; nt++)
#pragma unroll
      for (int kh = 0; kh < 2; kh++)
        bk[nt][kh] = *(const s16x8*)&Ks[cur][swz(nt * 16 + lrow, kh * 4 + lg)];

    f32x4 sf[2][4];
    __builtin_amdgcn_s_setprio(1);
#pragma unroll
    for (int mt = 0; mt < 2; mt++)
#pragma unroll
      for (int nt = 0; nt < 4; nt++) {
        f32x4 z = fzero;
        z = mfma16(aq[mt][0], bk[nt][0], z);
        z = mfma16(aq[mt][1], bk[nt][1], z);
        sf[mt][nt] = z;
      }
    __builtin_amdgcn_s_setprio(0);

    // ---- p = exp2(s); accumulate per-lane partial row-sums; write P swizzled ----
#pragma unroll
    for (int mt = 0; mt < 2; mt++) {
      const int rowb = w * 32 + mt * 16 + lg * 4;
#pragma unroll
      for (int r = 0; r < 4; r++) {
        const int row = rowb + r;
        u16* prow = &Ps[row * 64 + (lrow & 7)];
        const int rm = row & 7;
        float acc_l = 0.f;
#pragma unroll
        for (int nt = 0; nt < 4; nt++) {
          float p = __builtin_amdgcn_exp2f(sf[mt][nt][r]);
          acc_l += p;
          prow[((nt * 2 + (lrow >> 3)) ^ rm) << 3] = f2bf_fast(p);
        }
        l_[mt][r] += acc_l;
      }
    }
    asm volatile("s_waitcnt lgkmcnt(0)" ::: "memory");  // P rows are wave-private

    // ---- O += P V ----
    s16x8 ap[2][2], bv[4][2];
#pragma unroll
    for (int mt = 0; mt < 2; mt++)
#pragma unroll
      for (int kh = 0; kh < 2; kh++)
        ap[mt][kh] = *(const s16x8*)&Ps[swz(w * 32 + mt * 16 + lrow, kh * 4 + lg)];
#pragma unroll
    for (int dt = 0; dt < 4; dt++)
#pragma unroll
      for (int kh = 0; kh < 2; kh++)
        bv[dt][kh] = *(const s16x8*)&VTs[cur][swz(dt * 16 + lrow, kh * 4 + lg)];
    __builtin_amdgcn_s_setprio(1);
#pragma unroll
    for (int mt = 0; mt < 2; mt++)
#pragma unroll
      for (int dt = 0; dt < 4; dt++) {
        o[mt][dt] = mfma16(ap[mt][0], bv[dt][0], o[mt][dt]);
        o[mt][dt] = mfma16(ap[mt][1], bv[dt][1], o[mt][dt]);
      }
    __builtin_amdgcn_s_setprio(0);

    // one barrier per tile: implicit vmcnt(0)+lgkmcnt(0) drains the stage,
    // and gates buffer reuse for the next iteration.
    __syncthreads();
  }

  // ---- normalize + write [B][N][H][64] bf16 ----
  const int b = bh >> 4, h = bh & 15;
#pragma unroll
  for (int mt = 0; mt < 2; mt++)
#pragma unroll
    for (int r = 0; r < 4; r++) {
      float lsum = l_[mt][r];
#pragma unroll
      for (int off = 1; off < 16; off <<= 1) lsum += __shfl_xor(lsum, off);
      const float inv = 1.0f / lsum;
      const int n = qt * 128 + w * 32 + mt * 16 + lg * 4 + r;
      const size_t base = (((size_t)b * 1024 + n) * 16 + h) * 64;
#pragma unroll
      for (int dt = 0; dt < 4; dt++)
        obuf[base + dt * 16 + lrow] = f2bf(o[mt][dt][r] * inv);
    }
}

// ---------- proj GEMM -> fp32 d_out ----------
__global__ __launch_bounds__(512, 2) void gemm_proj(
    const u16* __restrict__ A,   // attn bf16 [32768][1024]
    const u16* __restrict__ Bt,  // proj_w^T bf16 [1024][1024]
    const float* __restrict__ bias,
    float* __restrict__ out)
{
  __shared__ u16 lds[65536];   // 128 KB
  // XCD-aware bijective swizzle: nwg = 512 = 8 * 64
  const int bid = blockIdx.x;
  const int sb = (bid & 7) * 64 + (bid >> 3);
  const int bm = sb >> 2, bn = sb & 3;

  const f32x4 fzero = {0.f, 0.f, 0.f, 0.f};
  f32x4 acc[8][4];
#pragma unroll
  for (int i = 0; i < 8; i++)
#pragma unroll
    for (int j = 0; j < 4; j++) acc[i][j] = fzero;

  gemm_mainloop_8ph(A + (size_t)bm * 256 * 1024, Bt + (size_t)bn * 256 * 1024, lds, acc);

  const int t = threadIdx.x, l = t & 63, w = t >> 6;
  const int wm = w & 1, wn = w >> 1, lrow = l & 15, lg = l >> 4;
  const int colb = bn * 256 + wn * 64;
  float biasv[4];
#pragma unroll
  for (int nt = 0; nt < 4; nt++) biasv[nt] = bias[colb + nt * 16 + lrow];

#pragma unroll
  for (int mf = 0; mf < 8; mf++) {
#pragma unroll
    for (int r = 0; r < 4; r++) {
      const int rowg = bm * 256 + wm * 128 + mf * 16 + lg * 4 + r;
#pragma unroll
      for (int nt = 0; nt < 4; nt++) {
        const int col = colb + nt * 16 + lrow;
        out[(size_t)rowg * 1024 + col] = acc[mf][nt][r] + biasv[nt];
      }
    }
  }
}

// ---------- launch ----------
extern "C" void kernel_launch(void* const* d_in, const int* in_sizes, int n_in,
                              void* d_out, int out_size, void* d_ws, size_t ws_size,
                              hipStream_t stream) {
  const float* x      = (const float*)d_in[0];
  const float* qkv_w  = (const float*)d_in[1];
  const float* qkv_b  = (const float*)d_in[2];
  const float* proj_w = (const float*)d_in[3];
  const float* proj_b = (const float*)d_in[4];
  const float* q_gam  = (const float*)d_in[5];
  const float* k_gam  = (const float*)d_in[6];

  char* ws = (char*)d_ws;
  u16*   xb   = (u16*)(ws);                    // 64 MB (x bf16; later aliased by attn out)
  u16*   qb   = (u16*)(ws + 67108864);         // 64 MB
  u16*   kb   = (u16*)(ws + 134217728);        // 64 MB
  u16*   vb   = (u16*)(ws + 201326592);        // 64 MB  (V^T per head)
  u16*   wqT  = (u16*)(ws + 268435456);        // 6 MB
  u16*   wpT  = (u16*)(ws + 274726912);        // 2 MB
  float* cosT = (float*)(ws + 276824064);      // 256 KB
  float* sinT = (float*)(ws + 277086208);      // 256 KB
  u16*   attn = xb;                            // reuse: x bf16 dead after QKV GEMM

  cvt_bf16<<<32768, 256, 0, stream>>>(x, xb, (size_t)33554432);
  transpose_cvt<<<dim3(48, 16), 256, 0, stream>>>(qkv_w, wqT, 1024, 3072);
  transpose_cvt<<<dim3(16, 16), 256, 0, stream>>>(proj_w, wpT, 1024, 1024);
  rope_tables_kernel<<<1024, 64, 0, stream>>>(cosT, sinT);

  gemm_qkv<<<dim3(1536), dim3(512), 0, stream>>>(xb, wqT, qkv_b, q_gam, k_gam,
                                                 cosT, sinT, qb, kb, vb);
  attn_kernel<<<4096, 256, 0, stream>>>(qb, kb, vb, attn);
  gemm_proj<<<dim3(512), dim3(512), 0, stream>>>(attn, wpT, proj_b, (float*)d_out);
}

// Round 4
// 713.559 us; speedup vs baseline: 1.0606x; 1.0606x over previous
//
#include <hip/hip_runtime.h>
#include <stdint.h>

typedef float f32x4 __attribute__((ext_vector_type(4)));
typedef float f32x16 __attribute__((ext_vector_type(16)));
typedef short s16x8 __attribute__((ext_vector_type(8)));
typedef unsigned short u16;

// ---------- helpers ----------
__device__ __forceinline__ u16 f2bf(float f) {
  union { float f; uint32_t u; } c; c.f = f;
  uint32_t u = c.u;
  u = (u + 0x7fffu + ((u >> 16) & 1u)) >> 16;   // RNE
  return (u16)u;
}

__device__ __forceinline__ void gload16(const void* g, void* lds) {
  __builtin_amdgcn_global_load_lds(
      (const __attribute__((address_space(1))) void*)g,
      (__attribute__((address_space(3))) void*)lds, 16, 0, 0);
}

__device__ __forceinline__ f32x4 mfma16(s16x8 a, s16x8 b, f32x4 c) {
  return __builtin_amdgcn_mfma_f32_16x16x32_bf16(a, b, c, 0, 0, 0);
}

__device__ __forceinline__ f32x16 mfma32(s16x8 a, s16x8 b, f32x16 c) {
  return __builtin_amdgcn_mfma_f32_32x32x16_bf16(a, b, c, 0, 0, 0);
}

// swizzled offset into an unpadded [rows][64] u16 tile: element block (row, c8)
__device__ __forceinline__ int swz(int row, int c8) {
  return row * 64 + ((c8 ^ (row & 7)) << 3);
}

// ---------- small prep kernels ----------
__global__ void cvt_bf16(const float* __restrict__ in, u16* __restrict__ out, size_t n) {
  size_t i = ((size_t)blockIdx.x * blockDim.x + threadIdx.x) * 4;
  if (i < n) {
    float4 v = *(const float4*)&in[i];
    u16 o0 = f2bf(v.x), o1 = f2bf(v.y), o2 = f2bf(v.z), o3 = f2bf(v.w);
    uint2 packed;
    packed.x = (uint32_t)o0 | ((uint32_t)o1 << 16);
    packed.y = (uint32_t)o2 | ((uint32_t)o3 << 16);
    *(uint2*)&out[i] = packed;
  }
}

// tiled transpose: in [rows][cols] fp32 -> out [cols][rows] bf16. grid (cols/64, rows/64)
__global__ void transpose_cvt(const float* __restrict__ in, u16* __restrict__ out,
                              int rows, int cols) {
  __shared__ float tile[64][65];
  const int c0 = blockIdx.x * 64, r0 = blockIdx.y * 64;
  const int tr = threadIdx.x >> 6, tc = threadIdx.x & 63;
#pragma unroll
  for (int i = 0; i < 16; i++) {
    int r = i * 4 + tr;
    tile[r][tc] = in[(size_t)(r0 + r) * cols + c0 + tc];
  }
  __syncthreads();
#pragma unroll
  for (int i = 0; i < 16; i++) {
    int oc = i * 4 + tr;                 // column of `in`
    out[(size_t)(c0 + oc) * rows + r0 + tc] = f2bf(tile[tc][oc]);
  }
}

__global__ void rope_tables_kernel(float* __restrict__ cosT, float* __restrict__ sinT) {
  int n = blockIdx.x;        // 0..1023
  int d = threadIdx.x;       // 0..63
  int ph = n >> 5, pw = n & 31;
  int pos = (d < 32) ? ph : pw;
  int fi = d & 15;
  float freq = powf(10000.f, -(float)fi / 16.f);
  float ang = (float)pos * freq;
  cosT[n * 64 + d] = cosf(ang);
  sinT[n * 64 + d] = sinf(ang);
}

// ============================================================================
// 256x256 8-phase GEMM mainloop (T2 swizzle + T3/T4 counted vmcnt + T5 setprio)
// 512 thr / 8 waves (2M x 4N), BK=64, LDS 128KB dbuf.  (unchanged from R1)
// ============================================================================

#define PH_MID \
  __builtin_amdgcn_sched_barrier(0); \
  __builtin_amdgcn_s_barrier(); \
  asm volatile("s_waitcnt lgkmcnt(0)" ::: "memory"); \
  __builtin_amdgcn_sched_barrier(0); \
  __builtin_amdgcn_s_setprio(1);

#define PH_END \
  __builtin_amdgcn_s_setprio(0); \
  __builtin_amdgcn_sched_barrier(0); \
  __builtin_amdgcn_s_barrier(); \
  __builtin_amdgcn_sched_barrier(0);

#define STAGE(ldsoff, g) do { \
    gload16((g) + (size_t)(w8 + srow) * 1024 + sc8 * 8,       &lds[(ldsoff) + w8 * 64]); \
    gload16((g) + (size_t)(w8 + srow + 64) * 1024 + sc8 * 8,  &lds[(ldsoff) + (w8 + 64) * 64]); \
  } while (0)

#define RD_A(dst, BUF, mh) \
  _Pragma("unroll") \
  for (int mi = 0; mi < 4; mi++) { \
    dst[mi][0] = *(const s16x8*)&lds[(BUF) * 32768 + arow0 + ((mh) * 64 + mi * 16) * 64 + swz0]; \
    dst[mi][1] = *(const s16x8*)&lds[(BUF) * 32768 + arow0 + ((mh) * 64 + mi * 16) * 64 + swz1]; \
  }

#define RD_B(dst, BUF, nh) \
  _Pragma("unroll") \
  for (int ni = 0; ni < 2; ni++) { \
    dst[ni][0] = *(const s16x8*)&lds[(BUF) * 32768 + 16384 + brow0 + ((nh) * 32 + ni * 16) * 64 + swz0]; \
    dst[ni][1] = *(const s16x8*)&lds[(BUF) * 32768 + 16384 + brow0 + ((nh) * 32 + ni * 16) * 64 + swz1]; \
  }

#define MFMA_QUAD(af, bfr, mh, nh) \
  _Pragma("unroll") \
  for (int mi = 0; mi < 4; mi++) \
    _Pragma("unroll") \
    for (int ni = 0; ni < 2; ni++) { \
      acc[(mh) * 4 + mi][(nh) * 2 + ni] = mfma16(af[mi][0], bfr[ni][0], acc[(mh) * 4 + mi][(nh) * 2 + ni]); \
      acc[(mh) * 4 + mi][(nh) * 2 + ni] = mfma16(af[mi][1], bfr[ni][1], acc[(mh) * 4 + mi][(nh) * 2 + ni]); \
    }

// MODE: 0 = steady; 1 = kt==14 (prefetch A only, vmcnt(0)); 2 = kt==15 (no prefetch)
#define KTILE(BUF, KT, MODE) do { \
    s16x8 a0f[4][2], a1f[4][2], b0f[2][2], b1f[2][2]; \
    /* P1 */ \
    RD_A(a0f, BUF, 0); \
    RD_B(b0f, BUF, 0); \
    if ((MODE) < 2) STAGE((1 - (BUF)) * 32768, Ag + (size_t)((KT) + 1) * 64); \
    PH_MID; MFMA_QUAD(a0f, b0f, 0, 0); PH_END; \
    /* P2 */ \
    RD_B(b1f, BUF, 1); \
    if ((MODE) < 2) STAGE((1 - (BUF)) * 32768 + 8192, Ag + (size_t)128 * 1024 + ((KT) + 1) * 64); \
    PH_MID; MFMA_QUAD(a0f, b1f, 0, 1); PH_END; \
    /* P3 */ \
    RD_A(a1f, BUF, 1); \
    if ((MODE) == 0) STAGE((BUF) * 32768 + 16384, Bg + (size_t)((KT) + 2) * 64); \
    PH_MID; MFMA_QUAD(a1f, b1f, 1, 1); PH_END; \
    /* P4 */ \
    if ((MODE) == 0) STAGE((BUF) * 32768 + 16384 + 8192, Bg + (size_t)128 * 1024 + ((KT) + 2) * 64); \
    PH_MID; MFMA_QUAD(a1f, b0f, 1, 0); \
    __builtin_amdgcn_s_setprio(0); \
    if ((MODE) == 0) asm volatile("s_waitcnt vmcnt(4)" ::: "memory"); \
    if ((MODE) == 1) asm volatile("s_waitcnt vmcnt(0)" ::: "memory"); \
    __builtin_amdgcn_sched_barrier(0); \
    __builtin_amdgcn_s_barrier(); \
    __builtin_amdgcn_sched_barrier(0); \
  } while (0)

__device__ __forceinline__ void gemm_mainloop_8ph(
    const u16* __restrict__ Ag, const u16* __restrict__ Bg,
    u16* lds, f32x4 (&acc)[8][4])
{
  const int t = threadIdx.x;
  const int l = t & 63, w = t >> 6;
  const int wm = w & 1, wn = w >> 1;
  const int lrow = l & 15, lg = l >> 4;
  const int srow = l >> 3, sc8 = (l & 7) ^ srow;   // pre-swizzled global chunk
  const int w8 = w * 8;
  const int swz0 = ((0 + lg) ^ (lrow & 7)) << 3;   // kh = 0 (K 0..31)
  const int swz1 = ((4 + lg) ^ (lrow & 7)) << 3;   // kh = 1 (K 32..63)
  const int arow0 = (wm * 128 + lrow) * 64;
  const int brow0 = (wn * 64 + lrow) * 64;

  STAGE(0,                 Ag);
  STAGE(8192,              Ag + (size_t)128 * 1024);
  STAGE(16384,             Bg);
  STAGE(16384 + 8192,      Bg + (size_t)128 * 1024);
  STAGE(32768 + 16384,          Bg + 64);
  STAGE(32768 + 16384 + 8192,   Bg + (size_t)128 * 1024 + 64);
  asm volatile("s_waitcnt vmcnt(4)" ::: "memory");   // kt0 complete; {B0,B1}_1 in flight
  __builtin_amdgcn_sched_barrier(0);
  __builtin_amdgcn_s_barrier();
  __builtin_amdgcn_sched_barrier(0);

#pragma unroll 1
  for (int kt = 0; kt < 14; kt += 2) {
    KTILE(0, kt, 0);
    KTILE(1, kt + 1, 0);
  }
  KTILE(0, 14, 1);
  KTILE(1, 15, 2);
}

// ---------- QKV GEMM + bias + RMSNorm(q,k) + RoPE + q-scale ----------
// q/k written [B*H][N][64]; v written TRANSPOSED per head: [B*H][64][N]
__global__ __launch_bounds__(512, 2) void gemm_qkv(
    const u16* __restrict__ A,   // x bf16 [32768][1024]
    const u16* __restrict__ Bt,  // qkv_w^T bf16 [3072][1024]
    const float* __restrict__ bias,
    const float* __restrict__ qgam, const float* __restrict__ kgam,
    const float* __restrict__ cosT, const float* __restrict__ sinT,
    u16* __restrict__ qb, u16* __restrict__ kb, u16* __restrict__ vb)
{
  __shared__ u16 lds[65536];   // 128 KB
  // XCD-aware bijective swizzle: nwg = 1536 = 8 * 192
  const int bid = blockIdx.x;
  const int sb = (bid & 7) * 192 + (bid >> 3);
  const int bm = sb / 12, bn = sb % 12;

  const f32x4 fzero = {0.f, 0.f, 0.f, 0.f};
  f32x4 acc[8][4];
#pragma unroll
  for (int i = 0; i < 8; i++)
#pragma unroll
    for (int j = 0; j < 4; j++) acc[i][j] = fzero;

  gemm_mainloop_8ph(A + (size_t)bm * 256 * 1024, Bt + (size_t)bn * 256 * 1024, lds, acc);

  const int t = threadIdx.x, l = t & 63, w = t >> 6;
  const int wm = w & 1, wn = w >> 1, lrow = l & 15, lg = l >> 4;
  const int colb = bn * 256 + wn * 64;       // 64-aligned -> single head per wave
  const int s = colb >> 10;                  // 0=q 1=k 2=v
  const int h = (colb & 1023) >> 6;

  float biasv[4];
#pragma unroll
  for (int nt = 0; nt < 4; nt++) biasv[nt] = bias[colb + nt * 16 + lrow];

  if (s < 2) {
    u16* dst = (s == 0) ? qb : kb;
    const float mul = (s == 0) ? 0.18033688011112042f : 1.0f;  // 0.125*log2(e) folded into q
    const float* gamma = (s == 0) ? qgam : kgam;
    float g[4];
#pragma unroll
    for (int nt = 0; nt < 4; nt++) g[nt] = gamma[nt * 16 + lrow] * mul;  // fold q-scale
#pragma unroll
    for (int mf = 0; mf < 8; mf++) {
#pragma unroll
      for (int r = 0; r < 4; r++) {
        const int rowg = bm * 256 + wm * 128 + mf * 16 + lg * 4 + r;
        const int b = rowg >> 10, np = rowg & 1023;
        float tmp[4]; float sq = 0.f;
#pragma unroll
        for (int nt = 0; nt < 4; nt++) {
          float v = acc[mf][nt][r] + biasv[nt];
          tmp[nt] = v; sq += v * v;
        }
#pragma unroll
        for (int off = 1; off < 16; off <<= 1) sq += __shfl_xor(sq, off);
        const float rstd = rsqrtf(sq * 0.015625f + 1e-6f);
#pragma unroll
        for (int nt = 0; nt < 4; nt++) tmp[nt] *= rstd * g[nt];
        const size_t base = (((size_t)(b * 16 + h)) * 1024 + np) * 64;
#pragma unroll
        for (int nt = 0; nt < 4; nt++) {
          const int d = nt * 16 + lrow;
          const float cv = cosT[np * 64 + d], sv = sinT[np * 64 + d];
          const float rh = (nt < 2) ? -tmp[nt + 2] : tmp[nt - 2];
          dst[base + d] = f2bf(tmp[nt] * cv + rh * sv);
        }
      }
    }
  } else {
    // V transposed: vb[(bh*64 + d)*1024 + np]  (R1 epilogue — measured fastest)
#pragma unroll
    for (int mf = 0; mf < 8; mf++) {
#pragma unroll
      for (int r = 0; r < 4; r++) {
        const int rowg = bm * 256 + wm * 128 + mf * 16 + lg * 4 + r;
        const int b = rowg >> 10, np = rowg & 1023;
        const size_t hb = ((size_t)(b * 16 + h)) * 64;
#pragma unroll
        for (int nt = 0; nt < 4; nt++) {
          const int d = nt * 16 + lrow;
          vb[(hb + d) * 1024 + np] = f2bf(acc[mf][nt][r] + biasv[nt]);
        }
      }
    }
  }
}

// ---------- flash attention: 32x32 swapped-QK^T, in-register softmax (T12) ----------
// grid 512*(1024/128); block 256 = 4 waves, each wave 32 q-rows.
// Q,K row-major per head [1024][64]; V transposed per head [64][1024].
// No running max: |s*scale*log2e| <= 11.5 (RMS-normed q,k), exp2 never overflows.
// S^T = mfma32(K, Q): lane (q=l&31, hi=l>>5) holds P[q][k], k = (r&3)+8*(r>>2)+4*hi
// (+16/32 per reg/block group). PV A-frags assembled IN REGISTERS via
// v_cvt_pk_bf16_f32 + v_permlane32_swap_b32 (operand order: LO-pair first,
// per the verified HK/m214v22 recipe) — no P LDS round-trip.
__global__ __launch_bounds__(256, 3) void attn_kernel(
    const u16* __restrict__ qbuf, const u16* __restrict__ kbuf,
    const u16* __restrict__ vtbuf, u16* __restrict__ obuf)
{
  __shared__ u16 Qs[128 * 64];     // 16KB, xor-swizzled
  __shared__ u16 Ks[2][64 * 64];   // 16KB double-buffered
  __shared__ u16 VTs[2][64 * 64];  // 16KB double-buffered (rows = d, cols = k)
  __shared__ float lsumS[4][32];   // per-wave row-sum broadcast
  const int bx = blockIdx.x;
  const int bh = bx >> 3, qt = bx & 7;
  const int t = threadIdx.x, l = t & 63, w = t >> 6;
  const int q31 = l & 31, hi = l >> 5;

  const u16* qg  = qbuf  + (size_t)bh * 65536 + (size_t)qt * 8192;
  const u16* kg0 = kbuf  + (size_t)bh * 65536;
  const u16* vt0 = vtbuf + (size_t)bh * 65536;

  // staging geometry: lane covers (row r0 + l>>3, swizzled chunk)
  const int srow = l >> 3;
  const int sc8  = (l & 7) ^ (srow & 7);

  // stage Q (128x64)
#pragma unroll
  for (int i = 0; i < 4; i++) {
    const int r0 = (w + i * 4) * 8;
    gload16(qg + (size_t)(r0 + srow) * 64 + sc8 * 8, &Qs[r0 * 64]);
  }
  // stage K,VT tile 0 into buffer 0
#pragma unroll
  for (int i = 0; i < 2; i++) {
    const int r0 = (w + i * 4) * 8;
    gload16(kg0 + (size_t)(r0 + srow) * 64 + sc8 * 8, &Ks[0][r0 * 64]);
    gload16(vt0 + (size_t)(r0 + srow) * 1024 + sc8 * 8, &VTs[0][r0 * 64]);
  }
  asm volatile("s_waitcnt vmcnt(0)" ::: "memory");
  __syncthreads();

  // Q B-frags held in regs whole loop: lane supplies Q[q31][ds*16 + hi*8 .. +8]
  s16x8 bq[4];
#pragma unroll
  for (int ds = 0; ds < 4; ds++)
    bq[ds] = *(const s16x8*)&Qs[swz(w * 32 + q31, ds * 2 + hi)];

  f32x16 o0, o1;
#pragma unroll
  for (int i = 0; i < 16; i++) { o0[i] = 0.f; o1[i] = 0.f; }
  float l_ = 0.f;

#pragma unroll 2
  for (int kt = 0; kt < 16; kt++) {
    const int cur = kt & 1;
    // issue next tile's stage first: latency hides under this tile's compute
    if (kt < 15) {
      const int kb = (kt + 1) * 64;
#pragma unroll
      for (int i = 0; i < 2; i++) {
        const int r0 = (w + i * 4) * 8;
        gload16(kg0 + (size_t)(kb + r0 + srow) * 64 + sc8 * 8, &Ks[cur ^ 1][r0 * 64]);
        gload16(vt0 + (size_t)(r0 + srow) * 1024 + kb + sc8 * 8, &VTs[cur ^ 1][r0 * 64]);
      }
    }

    // ---- S^T = K Q over d=64: two 32x32 k-blocks ----
    f32x16 s0, s1;
#pragma unroll
    for (int i = 0; i < 16; i++) { s0[i] = 0.f; s1[i] = 0.f; }
    __builtin_amdgcn_s_setprio(1);
#pragma unroll
    for (int ds = 0; ds < 4; ds++) {
      s16x8 ak0 = *(const s16x8*)&Ks[cur][swz(q31, ds * 2 + hi)];
      s16x8 ak1 = *(const s16x8*)&Ks[cur][swz(32 + q31, ds * 2 + hi)];
      s0 = mfma32(ak0, bq[ds], s0);
      s1 = mfma32(ak1, bq[ds], s1);
    }
    __builtin_amdgcn_s_setprio(0);

    // ---- p = exp2(s); lane-local row partial sum ----
    float p[32];
#pragma unroll
    for (int r = 0; r < 16; r++) p[r] = __builtin_amdgcn_exp2f(s0[r]);
#pragma unroll
    for (int r = 0; r < 16; r++) p[16 + r] = __builtin_amdgcn_exp2f(s1[r]);
    {
      float sm0 = 0.f, sm1 = 0.f, sm2 = 0.f, sm3 = 0.f;
#pragma unroll
      for (int r = 0; r < 8; r++) {
        sm0 += p[r]; sm1 += p[8 + r]; sm2 += p[16 + r]; sm3 += p[24 + r];
      }
      l_ += (sm0 + sm1) + (sm2 + sm3);
    }

    // ---- assemble PV A-frags in-register: 4 cvt_pk + 2 permlane swaps each ----
    // swap operand order: LOW-k pair first (HK/m214v22 recipe): after
    // swap(a1, a2): a1 = [a1_lo; a2_lo] (elems 0-1), a2 = [a1_hi; a2_hi] (elems 4-5)
    s16x8 pf[4];
#pragma unroll
    for (int j = 0; j < 4; j++) {
      uint32_t a1, b1, a2, b2;
      asm("v_cvt_pk_bf16_f32 %0, %1, %2" : "=v"(a1) : "v"(p[j * 8 + 0]), "v"(p[j * 8 + 1]));
      asm("v_cvt_pk_bf16_f32 %0, %1, %2" : "=v"(b1) : "v"(p[j * 8 + 2]), "v"(p[j * 8 + 3]));
      asm("v_cvt_pk_bf16_f32 %0, %1, %2" : "=v"(a2) : "v"(p[j * 8 + 4]), "v"(p[j * 8 + 5]));
      asm("v_cvt_pk_bf16_f32 %0, %1, %2" : "=v"(b2) : "v"(p[j * 8 + 6]), "v"(p[j * 8 + 7]));
      asm("v_permlane32_swap_b32 %0, %1" : "+v"(a1), "+v"(a2));
      asm("v_permlane32_swap_b32 %0, %1" : "+v"(b1), "+v"(b2));
      union { s16x8 v; uint32_t u[4]; } cvt;
      cvt.u[0] = a1; cvt.u[1] = b1; cvt.u[2] = a2; cvt.u[3] = b2;
      pf[j] = cvt.v;
    }

    // ---- O += P V : lane supplies V[j*16 + hi*8 .. +8][d-col] from VT rows ----
    __builtin_amdgcn_s_setprio(1);
#pragma unroll
    for (int j = 0; j < 4; j++) {
      s16x8 bv0 = *(const s16x8*)&VTs[cur][swz(q31, j * 2 + hi)];
      s16x8 bv1 = *(const s16x8*)&VTs[cur][swz(32 + q31, j * 2 + hi)];
      o0 = mfma32(pf[j], bv0, o0);
      o1 = mfma32(pf[j], bv1, o1);
    }
    __builtin_amdgcn_s_setprio(0);

    // one barrier per tile: implicit vmcnt(0)+lgkmcnt(0) drains the stage,
    // and gates buffer reuse for the next iteration.
    __syncthreads();
  }

  // ---- combine row-sum halves (lane ^ 32) via shuffle (alias-safe) ----
  l_ += __shfl_xor(l_, 32);
  if (l < 32) lsumS[w][q31] = 1.0f / l_;

  const int b = bh >> 4, h = bh & 15;
#pragma unroll
  for (int r = 0; r < 16; r++) {
    const int q = (r & 3) + 8 * (r >> 2) + 4 * hi;
    const float inv = lsumS[w][q];
    const int n = qt * 128 + w * 32 + q;
    const size_t base = (((size_t)b * 1024 + n) * 16 + h) * 64;
    obuf[base + q31]      = f2bf(o0[r] * inv);
    obuf[base + 32 + q31] = f2bf(o1[r] * inv);
  }
}

// ---------- proj GEMM -> fp32 d_out ----------
__global__ __launch_bounds__(512, 2) void gemm_proj(
    const u16* __restrict__ A,   // attn bf16 [32768][1024]
    const u16* __restrict__ Bt,  // proj_w^T bf16 [1024][1024]
    const float* __restrict__ bias,
    float* __restrict__ out)
{
  __shared__ u16 lds[65536];   // 128 KB
  // XCD-aware bijective swizzle: nwg = 512 = 8 * 64
  const int bid = blockIdx.x;
  const int sb = (bid & 7) * 64 + (bid >> 3);
  const int bm = sb >> 2, bn = sb & 3;

  const f32x4 fzero = {0.f, 0.f, 0.f, 0.f};
  f32x4 acc[8][4];
#pragma unroll
  for (int i = 0; i < 8; i++)
#pragma unroll
    for (int j = 0; j < 4; j++) acc[i][j] = fzero;

  gemm_mainloop_8ph(A + (size_t)bm * 256 * 1024, Bt + (size_t)bn * 256 * 1024, lds, acc);

  const int t = threadIdx.x, l = t & 63, w = t >> 6;
  const int wm = w & 1, wn = w >> 1, lrow = l & 15, lg = l >> 4;
  const int colb = bn * 256 + wn * 64;
  float biasv[4];
#pragma unroll
  for (int nt = 0; nt < 4; nt++) biasv[nt] = bias[colb + nt * 16 + lrow];

#pragma unroll
  for (int mf = 0; mf < 8; mf++) {
#pragma unroll
    for (int r = 0; r < 4; r++) {
      const int rowg = bm * 256 + wm * 128 + mf * 16 + lg * 4 + r;
#pragma unroll
      for (int nt = 0; nt < 4; nt++) {
        const int col = colb + nt * 16 + lrow;
        out[(size_t)rowg * 1024 + col] = acc[mf][nt][r] + biasv[nt];
      }
    }
  }
}

// ---------- launch ----------
extern "C" void kernel_launch(void* const* d_in, const int* in_sizes, int n_in,
                              void* d_out, int out_size, void* d_ws, size_t ws_size,
                              hipStream_t stream) {
  const float* x      = (const float*)d_in[0];
  const float* qkv_w  = (const float*)d_in[1];
  const float* qkv_b  = (const float*)d_in[2];
  const float* proj_w = (const float*)d_in[3];
  const float* proj_b = (const float*)d_in[4];
  const float* q_gam  = (const float*)d_in[5];
  const float* k_gam  = (const float*)d_in[6];

  char* ws = (char*)d_ws;
  u16*   xb   = (u16*)(ws);                    // 64 MB (x bf16; later aliased by attn out)
  u16*   qb   = (u16*)(ws + 67108864);         // 64 MB
  u16*   kb   = (u16*)(ws + 134217728);        // 64 MB
  u16*   vb   = (u16*)(ws + 201326592);        // 64 MB  (V^T per head)
  u16*   wqT  = (u16*)(ws + 268435456);        // 6 MB
  u16*   wpT  = (u16*)(ws + 274726912);        // 2 MB
  float* cosT = (float*)(ws + 276824064);      // 256 KB
  float* sinT = (float*)(ws + 277086208);      // 256 KB
  u16*   attn = xb;                            // reuse: x bf16 dead after QKV GEMM

  cvt_bf16<<<32768, 256, 0, stream>>>(x, xb, (size_t)33554432);
  transpose_cvt<<<dim3(48, 16), 256, 0, stream>>>(qkv_w, wqT, 1024, 3072);
  transpose_cvt<<<dim3(16, 16), 256, 0, stream>>>(proj_w, wpT, 1024, 1024);
  rope_tables_kernel<<<1024, 64, 0, stream>>>(cosT, sinT);

  gemm_qkv<<<dim3(1536), dim3(512), 0, stream>>>(xb, wqT, qkv_b, q_gam, k_gam,
                                                 cosT, sinT, qb, kb, vb);
  attn_kernel<<<4096, 256, 0, stream>>>(qb, kb, vb, attn);
  gemm_proj<<<dim3(512), dim3(512), 0, stream>>>(attn, wpT, proj_b, (float*)d_out);
}

// Round 5
// 691.145 us; speedup vs baseline: 1.0950x; 1.0324x over previous
//
#include <hip/hip_runtime.h>
#include <stdint.h>

typedef float f32x4 __attribute__((ext_vector_type(4)));
typedef float f32x16 __attribute__((ext_vector_type(16)));
typedef short s16x8 __attribute__((ext_vector_type(8)));
typedef unsigned short u16;

// ---------- helpers ----------
__device__ __forceinline__ u16 f2bf(float f) {
  union { float f; uint32_t u; } c; c.f = f;
  uint32_t u = c.u;
  u = (u + 0x7fffu + ((u >> 16) & 1u)) >> 16;   // RNE
  return (u16)u;
}

__device__ __forceinline__ void gload16(const void* g, void* lds) {
  __builtin_amdgcn_global_load_lds(
      (const __attribute__((address_space(1))) void*)g,
      (__attribute__((address_space(3))) void*)lds, 16, 0, 0);
}

__device__ __forceinline__ f32x4 mfma16(s16x8 a, s16x8 b, f32x4 c) {
  return __builtin_amdgcn_mfma_f32_16x16x32_bf16(a, b, c, 0, 0, 0);
}

__device__ __forceinline__ f32x16 mfma32(s16x8 a, s16x8 b, f32x16 c) {
  return __builtin_amdgcn_mfma_f32_32x32x16_bf16(a, b, c, 0, 0, 0);
}

// swizzled offset into an unpadded [rows][64] u16 tile: element block (row, c8)
__device__ __forceinline__ int swz(int row, int c8) {
  return row * 64 + ((c8 ^ (row & 7)) << 3);
}

// ---------- small prep kernels ----------
__global__ void cvt_bf16(const float* __restrict__ in, u16* __restrict__ out, size_t n) {
  size_t i = ((size_t)blockIdx.x * blockDim.x + threadIdx.x) * 4;
  if (i < n) {
    float4 v = *(const float4*)&in[i];
    u16 o0 = f2bf(v.x), o1 = f2bf(v.y), o2 = f2bf(v.z), o3 = f2bf(v.w);
    uint2 packed;
    packed.x = (uint32_t)o0 | ((uint32_t)o1 << 16);
    packed.y = (uint32_t)o2 | ((uint32_t)o3 << 16);
    *(uint2*)&out[i] = packed;
  }
}

// tiled transpose: in [rows][cols] fp32 -> out [cols][rows] bf16. grid (cols/64, rows/64)
__global__ void transpose_cvt(const float* __restrict__ in, u16* __restrict__ out,
                              int rows, int cols) {
  __shared__ float tile[64][65];
  const int c0 = blockIdx.x * 64, r0 = blockIdx.y * 64;
  const int tr = threadIdx.x >> 6, tc = threadIdx.x & 63;
#pragma unroll
  for (int i = 0; i < 16; i++) {
    int r = i * 4 + tr;
    tile[r][tc] = in[(size_t)(r0 + r) * cols + c0 + tc];
  }
  __syncthreads();
#pragma unroll
  for (int i = 0; i < 16; i++) {
    int oc = i * 4 + tr;                 // column of `in`
    out[(size_t)(c0 + oc) * rows + r0 + tc] = f2bf(tile[tc][oc]);
  }
}

__global__ void rope_tables_kernel(float* __restrict__ cosT, float* __restrict__ sinT) {
  int n = blockIdx.x;        // 0..1023
  int d = threadIdx.x;       // 0..63
  int ph = n >> 5, pw = n & 31;
  int pos = (d < 32) ? ph : pw;
  int fi = d & 15;
  float freq = powf(10000.f, -(float)fi / 16.f);
  float ang = (float)pos * freq;
  cosT[n * 64 + d] = cosf(ang);
  sinT[n * 64 + d] = sinf(ang);
}

// ============================================================================
// 256x256 8-phase GEMM mainloop (T2 swizzle + T3/T4 counted vmcnt + T5 setprio)
// 512 thr / 8 waves (2M x 4N), BK=64, LDS 128KB dbuf.  (unchanged from R1)
// ============================================================================

#define PH_MID \
  __builtin_amdgcn_sched_barrier(0); \
  __builtin_amdgcn_s_barrier(); \
  asm volatile("s_waitcnt lgkmcnt(0)" ::: "memory"); \
  __builtin_amdgcn_sched_barrier(0); \
  __builtin_amdgcn_s_setprio(1);

#define PH_END \
  __builtin_amdgcn_s_setprio(0); \
  __builtin_amdgcn_sched_barrier(0); \
  __builtin_amdgcn_s_barrier(); \
  __builtin_amdgcn_sched_barrier(0);

#define STAGE(ldsoff, g) do { \
    gload16((g) + (size_t)(w8 + srow) * 1024 + sc8 * 8,       &lds[(ldsoff) + w8 * 64]); \
    gload16((g) + (size_t)(w8 + srow + 64) * 1024 + sc8 * 8,  &lds[(ldsoff) + (w8 + 64) * 64]); \
  } while (0)

#define RD_A(dst, BUF, mh) \
  _Pragma("unroll") \
  for (int mi = 0; mi < 4; mi++) { \
    dst[mi][0] = *(const s16x8*)&lds[(BUF) * 32768 + arow0 + ((mh) * 64 + mi * 16) * 64 + swz0]; \
    dst[mi][1] = *(const s16x8*)&lds[(BUF) * 32768 + arow0 + ((mh) * 64 + mi * 16) * 64 + swz1]; \
  }

#define RD_B(dst, BUF, nh) \
  _Pragma("unroll") \
  for (int ni = 0; ni < 2; ni++) { \
    dst[ni][0] = *(const s16x8*)&lds[(BUF) * 32768 + 16384 + brow0 + ((nh) * 32 + ni * 16) * 64 + swz0]; \
    dst[ni][1] = *(const s16x8*)&lds[(BUF) * 32768 + 16384 + brow0 + ((nh) * 32 + ni * 16) * 64 + swz1]; \
  }

#define MFMA_QUAD(af, bfr, mh, nh) \
  _Pragma("unroll") \
  for (int mi = 0; mi < 4; mi++) \
    _Pragma("unroll") \
    for (int ni = 0; ni < 2; ni++) { \
      acc[(mh) * 4 + mi][(nh) * 2 + ni] = mfma16(af[mi][0], bfr[ni][0], acc[(mh) * 4 + mi][(nh) * 2 + ni]); \
      acc[(mh) * 4 + mi][(nh) * 2 + ni] = mfma16(af[mi][1], bfr[ni][1], acc[(mh) * 4 + mi][(nh) * 2 + ni]); \
    }

// MODE: 0 = steady; 1 = kt==14 (prefetch A only, vmcnt(0)); 2 = kt==15 (no prefetch)
#define KTILE(BUF, KT, MODE) do { \
    s16x8 a0f[4][2], a1f[4][2], b0f[2][2], b1f[2][2]; \
    /* P1 */ \
    RD_A(a0f, BUF, 0); \
    RD_B(b0f, BUF, 0); \
    if ((MODE) < 2) STAGE((1 - (BUF)) * 32768, Ag + (size_t)((KT) + 1) * 64); \
    PH_MID; MFMA_QUAD(a0f, b0f, 0, 0); PH_END; \
    /* P2 */ \
    RD_B(b1f, BUF, 1); \
    if ((MODE) < 2) STAGE((1 - (BUF)) * 32768 + 8192, Ag + (size_t)128 * 1024 + ((KT) + 1) * 64); \
    PH_MID; MFMA_QUAD(a0f, b1f, 0, 1); PH_END; \
    /* P3 */ \
    RD_A(a1f, BUF, 1); \
    if ((MODE) == 0) STAGE((BUF) * 32768 + 16384, Bg + (size_t)((KT) + 2) * 64); \
    PH_MID; MFMA_QUAD(a1f, b1f, 1, 1); PH_END; \
    /* P4 */ \
    if ((MODE) == 0) STAGE((BUF) * 32768 + 16384 + 8192, Bg + (size_t)128 * 1024 + ((KT) + 2) * 64); \
    PH_MID; MFMA_QUAD(a1f, b0f, 1, 0); \
    __builtin_amdgcn_s_setprio(0); \
    if ((MODE) == 0) asm volatile("s_waitcnt vmcnt(4)" ::: "memory"); \
    if ((MODE) == 1) asm volatile("s_waitcnt vmcnt(0)" ::: "memory"); \
    __builtin_amdgcn_sched_barrier(0); \
    __builtin_amdgcn_s_barrier(); \
    __builtin_amdgcn_sched_barrier(0); \
  } while (0)

__device__ __forceinline__ void gemm_mainloop_8ph(
    const u16* __restrict__ Ag, const u16* __restrict__ Bg,
    u16* lds, f32x4 (&acc)[8][4])
{
  const int t = threadIdx.x;
  const int l = t & 63, w = t >> 6;
  const int wm = w & 1, wn = w >> 1;
  const int lrow = l & 15, lg = l >> 4;
  const int srow = l >> 3, sc8 = (l & 7) ^ srow;   // pre-swizzled global chunk
  const int w8 = w * 8;
  const int swz0 = ((0 + lg) ^ (lrow & 7)) << 3;   // kh = 0 (K 0..31)
  const int swz1 = ((4 + lg) ^ (lrow & 7)) << 3;   // kh = 1 (K 32..63)
  const int arow0 = (wm * 128 + lrow) * 64;
  const int brow0 = (wn * 64 + lrow) * 64;

  STAGE(0,                 Ag);
  STAGE(8192,              Ag + (size_t)128 * 1024);
  STAGE(16384,             Bg);
  STAGE(16384 + 8192,      Bg + (size_t)128 * 1024);
  STAGE(32768 + 16384,          Bg + 64);
  STAGE(32768 + 16384 + 8192,   Bg + (size_t)128 * 1024 + 64);
  asm volatile("s_waitcnt vmcnt(4)" ::: "memory");   // kt0 complete; {B0,B1}_1 in flight
  __builtin_amdgcn_sched_barrier(0);
  __builtin_amdgcn_s_barrier();
  __builtin_amdgcn_sched_barrier(0);

#pragma unroll 1
  for (int kt = 0; kt < 14; kt += 2) {
    KTILE(0, kt, 0);
    KTILE(1, kt + 1, 0);
  }
  KTILE(0, 14, 1);
  KTILE(1, 15, 2);
}

// ---------- QKV GEMM + bias + RMSNorm(q,k) + RoPE + q-scale ----------
// q/k written [B*H][N][64]; v written TRANSPOSED per head: [B*H][64][N]
__global__ __launch_bounds__(512, 2) void gemm_qkv(
    const u16* __restrict__ A,   // x bf16 [32768][1024]
    const u16* __restrict__ Bt,  // qkv_w^T bf16 [3072][1024]
    const float* __restrict__ bias,
    const float* __restrict__ qgam, const float* __restrict__ kgam,
    const float* __restrict__ cosT, const float* __restrict__ sinT,
    u16* __restrict__ qb, u16* __restrict__ kb, u16* __restrict__ vb)
{
  __shared__ u16 lds[65536];   // 128 KB
  // XCD-aware bijective swizzle: nwg = 1536 = 8 * 192
  const int bid = blockIdx.x;
  const int sb = (bid & 7) * 192 + (bid >> 3);
  const int bm = sb / 12, bn = sb % 12;

  const f32x4 fzero = {0.f, 0.f, 0.f, 0.f};
  f32x4 acc[8][4];
#pragma unroll
  for (int i = 0; i < 8; i++)
#pragma unroll
    for (int j = 0; j < 4; j++) acc[i][j] = fzero;

  gemm_mainloop_8ph(A + (size_t)bm * 256 * 1024, Bt + (size_t)bn * 256 * 1024, lds, acc);

  const int t = threadIdx.x, l = t & 63, w = t >> 6;
  const int wm = w & 1, wn = w >> 1, lrow = l & 15, lg = l >> 4;
  const int colb = bn * 256 + wn * 64;       // 64-aligned -> single head per wave
  const int s = colb >> 10;                  // 0=q 1=k 2=v
  const int h = (colb & 1023) >> 6;

  float biasv[4];
#pragma unroll
  for (int nt = 0; nt < 4; nt++) biasv[nt] = bias[colb + nt * 16 + lrow];

  if (s < 2) {
    u16* dst = (s == 0) ? qb : kb;
    const float mul = (s == 0) ? 0.18033688011112042f : 1.0f;  // 0.125*log2(e) folded into q
    const float* gamma = (s == 0) ? qgam : kgam;
    float g[4];
#pragma unroll
    for (int nt = 0; nt < 4; nt++) g[nt] = gamma[nt * 16 + lrow] * mul;  // fold q-scale
#pragma unroll
    for (int mf = 0; mf < 8; mf++) {
#pragma unroll
      for (int r = 0; r < 4; r++) {
        const int rowg = bm * 256 + wm * 128 + mf * 16 + lg * 4 + r;
        const int b = rowg >> 10, np = rowg & 1023;
        float tmp[4]; float sq = 0.f;
#pragma unroll
        for (int nt = 0; nt < 4; nt++) {
          float v = acc[mf][nt][r] + biasv[nt];
          tmp[nt] = v; sq += v * v;
        }
#pragma unroll
        for (int off = 1; off < 16; off <<= 1) sq += __shfl_xor(sq, off);
        const float rstd = rsqrtf(sq * 0.015625f + 1e-6f);
#pragma unroll
        for (int nt = 0; nt < 4; nt++) tmp[nt] *= rstd * g[nt];
        const size_t base = (((size_t)(b * 16 + h)) * 1024 + np) * 64;
#pragma unroll
        for (int nt = 0; nt < 4; nt++) {
          const int d = nt * 16 + lrow;
          const float cv = cosT[np * 64 + d], sv = sinT[np * 64 + d];
          const float rh = (nt < 2) ? -tmp[nt + 2] : tmp[nt - 2];
          dst[base + d] = f2bf(tmp[nt] * cv + rh * sv);
        }
      }
    }
  } else {
    // V transposed: vb[(bh*64 + d)*1024 + np]  (R1 epilogue — measured fastest)
#pragma unroll
    for (int mf = 0; mf < 8; mf++) {
#pragma unroll
      for (int r = 0; r < 4; r++) {
        const int rowg = bm * 256 + wm * 128 + mf * 16 + lg * 4 + r;
        const int b = rowg >> 10, np = rowg & 1023;
        const size_t hb = ((size_t)(b * 16 + h)) * 64;
#pragma unroll
        for (int nt = 0; nt < 4; nt++) {
          const int d = nt * 16 + lrow;
          vb[(hb + d) * 1024 + np] = f2bf(acc[mf][nt][r] + biasv[nt]);
        }
      }
    }
  }
}

// ---------- flash attention: 32x32 swapped-QK^T, 64 q-rows/wave ----------
// grid 512*(1024/256); block 256 = 4 waves, each wave 64 q-rows (2 q-blocks).
// K/V LDS fragments are reused across both q-blocks -> LDS reads per MFMA halved
// vs the 32-row/wave version (16 ds_read_b128 : 32 mfma32 per wave-tile).
// Q,K row-major per head [1024][64]; V transposed per head [64][1024].
// No running max: |s*scale*log2e| <= 11.5 (RMS-normed q,k), exp2 never overflows.
// S^T = mfma32(K, Q): lane (q=l&31, hi=l>>5) holds P[q][k], k = (r&3)+8*(r>>2)+4*hi.
// PV A-frags assembled IN REGISTERS via v_cvt_pk_bf16_f32 + v_permlane32_swap_b32
// (LO-pair first operand — verified R4).
__global__ __launch_bounds__(256, 2) void attn_kernel(
    const u16* __restrict__ qbuf, const u16* __restrict__ kbuf,
    const u16* __restrict__ vtbuf, u16* __restrict__ obuf)
{
  __shared__ u16 Qs[256 * 64];     // 32KB, xor-swizzled
  __shared__ u16 Ks[2][64 * 64];   // 16KB double-buffered
  __shared__ u16 VTs[2][64 * 64];  // 16KB double-buffered (rows = d, cols = k)
  __shared__ float lsumS[4][2][32];
  const int bx = blockIdx.x;
  const int bh = bx >> 2, qt = bx & 3;
  const int t = threadIdx.x, l = t & 63, w = t >> 6;
  const int q31 = l & 31, hi = l >> 5;

  const u16* qg  = qbuf  + (size_t)bh * 65536 + (size_t)qt * 16384;
  const u16* kg0 = kbuf  + (size_t)bh * 65536;
  const u16* vt0 = vtbuf + (size_t)bh * 65536;

  // staging geometry: lane covers (row r0 + l>>3, swizzled chunk)
  const int srow = l >> 3;
  const int sc8  = (l & 7) ^ (srow & 7);

  // stage Q (256x64)
#pragma unroll
  for (int i = 0; i < 8; i++) {
    const int r0 = (w + i * 4) * 8;
    gload16(qg + (size_t)(r0 + srow) * 64 + sc8 * 8, &Qs[r0 * 64]);
  }
  // stage K,VT tile 0 into buffer 0
#pragma unroll
  for (int i = 0; i < 2; i++) {
    const int r0 = (w + i * 4) * 8;
    gload16(kg0 + (size_t)(r0 + srow) * 64 + sc8 * 8, &Ks[0][r0 * 64]);
    gload16(vt0 + (size_t)(r0 + srow) * 1024 + sc8 * 8, &VTs[0][r0 * 64]);
  }
  asm volatile("s_waitcnt vmcnt(0)" ::: "memory");
  __syncthreads();

  // Q B-frags held in regs whole loop: lane supplies Q[row][ds*16 + hi*8 .. +8]
  s16x8 bq[2][4];
#pragma unroll
  for (int qb = 0; qb < 2; qb++)
#pragma unroll
    for (int ds = 0; ds < 4; ds++)
      bq[qb][ds] = *(const s16x8*)&Qs[swz(w * 64 + qb * 32 + q31, ds * 2 + hi)];

  f32x16 o[2][2];
#pragma unroll
  for (int qb = 0; qb < 2; qb++)
#pragma unroll
    for (int kb2 = 0; kb2 < 2; kb2++)
#pragma unroll
      for (int i = 0; i < 16; i++) o[qb][kb2][i] = 0.f;
  float l_[2] = {0.f, 0.f};

#pragma unroll 2
  for (int kt = 0; kt < 16; kt++) {
    const int cur = kt & 1;
    // issue next tile's stage first: latency hides under this tile's compute
    if (kt < 15) {
      const int kb = (kt + 1) * 64;
#pragma unroll
      for (int i = 0; i < 2; i++) {
        const int r0 = (w + i * 4) * 8;
        gload16(kg0 + (size_t)(kb + r0 + srow) * 64 + sc8 * 8, &Ks[cur ^ 1][r0 * 64]);
        gload16(vt0 + (size_t)(r0 + srow) * 1024 + kb + sc8 * 8, &VTs[cur ^ 1][r0 * 64]);
      }
    }

    // ---- S^T = K Q over d=64: two 32x32 k-blocks x two q-blocks ----
    // K frags loaded once per ds, reused for both q-blocks.
    f32x16 s[2][2];
#pragma unroll
    for (int qb = 0; qb < 2; qb++)
#pragma unroll
      for (int kb2 = 0; kb2 < 2; kb2++)
#pragma unroll
        for (int i = 0; i < 16; i++) s[qb][kb2][i] = 0.f;
    __builtin_amdgcn_s_setprio(1);
#pragma unroll
    for (int ds = 0; ds < 4; ds++) {
      s16x8 ak0 = *(const s16x8*)&Ks[cur][swz(q31, ds * 2 + hi)];
      s16x8 ak1 = *(const s16x8*)&Ks[cur][swz(32 + q31, ds * 2 + hi)];
      s[0][0] = mfma32(ak0, bq[0][ds], s[0][0]);
      s[0][1] = mfma32(ak1, bq[0][ds], s[0][1]);
      s[1][0] = mfma32(ak0, bq[1][ds], s[1][0]);
      s[1][1] = mfma32(ak1, bq[1][ds], s[1][1]);
    }
    __builtin_amdgcn_s_setprio(0);

    // ---- p = exp2(s); lane-local row partial sums; pack PV A-frags ----
    s16x8 pf[2][4];
#pragma unroll
    for (int qb = 0; qb < 2; qb++) {
      float p[32];
#pragma unroll
      for (int r = 0; r < 16; r++) p[r] = __builtin_amdgcn_exp2f(s[qb][0][r]);
#pragma unroll
      for (int r = 0; r < 16; r++) p[16 + r] = __builtin_amdgcn_exp2f(s[qb][1][r]);
      {
        float sm0 = 0.f, sm1 = 0.f, sm2 = 0.f, sm3 = 0.f;
#pragma unroll
        for (int r = 0; r < 8; r++) {
          sm0 += p[r]; sm1 += p[8 + r]; sm2 += p[16 + r]; sm3 += p[24 + r];
        }
        l_[qb] += (sm0 + sm1) + (sm2 + sm3);
      }
      // LO-pair first operand (verified R4): after swap(a1,a2):
      // a1 = [a1_lo; a2_lo] (frag elems 0-1), a2 = [a1_hi; a2_hi] (elems 4-5)
#pragma unroll
      for (int j = 0; j < 4; j++) {
        uint32_t a1, b1, a2, b2;
        asm("v_cvt_pk_bf16_f32 %0, %1, %2" : "=v"(a1) : "v"(p[j * 8 + 0]), "v"(p[j * 8 + 1]));
        asm("v_cvt_pk_bf16_f32 %0, %1, %2" : "=v"(b1) : "v"(p[j * 8 + 2]), "v"(p[j * 8 + 3]));
        asm("v_cvt_pk_bf16_f32 %0, %1, %2" : "=v"(a2) : "v"(p[j * 8 + 4]), "v"(p[j * 8 + 5]));
        asm("v_cvt_pk_bf16_f32 %0, %1, %2" : "=v"(b2) : "v"(p[j * 8 + 6]), "v"(p[j * 8 + 7]));
        asm("v_permlane32_swap_b32 %0, %1" : "+v"(a1), "+v"(a2));
        asm("v_permlane32_swap_b32 %0, %1" : "+v"(b1), "+v"(b2));
        union { s16x8 v; uint32_t u[4]; } cvt;
        cvt.u[0] = a1; cvt.u[1] = b1; cvt.u[2] = a2; cvt.u[3] = b2;
        pf[qb][j] = cvt.v;
      }
    }

    // ---- O += P V : V frags loaded once per j, reused for both q-blocks ----
    __builtin_amdgcn_s_setprio(1);
#pragma unroll
    for (int j = 0; j < 4; j++) {
      s16x8 bv0 = *(const s16x8*)&VTs[cur][swz(q31, j * 2 + hi)];
      s16x8 bv1 = *(const s16x8*)&VTs[cur][swz(32 + q31, j * 2 + hi)];
      o[0][0] = mfma32(pf[0][j], bv0, o[0][0]);
      o[0][1] = mfma32(pf[0][j], bv1, o[0][1]);
      o[1][0] = mfma32(pf[1][j], bv0, o[1][0]);
      o[1][1] = mfma32(pf[1][j], bv1, o[1][1]);
    }
    __builtin_amdgcn_s_setprio(0);

    // one barrier per tile: implicit vmcnt(0)+lgkmcnt(0) drains the stage,
    // and gates buffer reuse for the next iteration.
    __syncthreads();
  }

  // ---- combine row-sum halves (lane ^ 32) via shuffle (alias-safe) ----
#pragma unroll
  for (int qb = 0; qb < 2; qb++) {
    l_[qb] += __shfl_xor(l_[qb], 32);
    if (l < 32) lsumS[w][qb][q31] = 1.0f / l_[qb];
  }

  const int b = bh >> 4, h = bh & 15;
#pragma unroll
  for (int qb = 0; qb < 2; qb++)
#pragma unroll
    for (int r = 0; r < 16; r++) {
      const int q = (r & 3) + 8 * (r >> 2) + 4 * hi;
      const float inv = lsumS[w][qb][q];
      const int n = qt * 256 + w * 64 + qb * 32 + q;
      const size_t base = (((size_t)b * 1024 + n) * 16 + h) * 64;
      obuf[base + q31]      = f2bf(o[qb][0][r] * inv);
      obuf[base + 32 + q31] = f2bf(o[qb][1][r] * inv);
    }
}

// ---------- proj GEMM -> fp32 d_out ----------
__global__ __launch_bounds__(512, 2) void gemm_proj(
    const u16* __restrict__ A,   // attn bf16 [32768][1024]
    const u16* __restrict__ Bt,  // proj_w^T bf16 [1024][1024]
    const float* __restrict__ bias,
    float* __restrict__ out)
{
  __shared__ u16 lds[65536];   // 128 KB
  // XCD-aware bijective swizzle: nwg = 512 = 8 * 64
  const int bid = blockIdx.x;
  const int sb = (bid & 7) * 64 + (bid >> 3);
  const int bm = sb >> 2, bn = sb & 3;

  const f32x4 fzero = {0.f, 0.f, 0.f, 0.f};
  f32x4 acc[8][4];
#pragma unroll
  for (int i = 0; i < 8; i++)
#pragma unroll
    for (int j = 0; j < 4; j++) acc[i][j] = fzero;

  gemm_mainloop_8ph(A + (size_t)bm * 256 * 1024, Bt + (size_t)bn * 256 * 1024, lds, acc);

  const int t = threadIdx.x, l = t & 63, w = t >> 6;
  const int wm = w & 1, wn = w >> 1, lrow = l & 15, lg = l >> 4;
  const int colb = bn * 256 + wn * 64;
  float biasv[4];
#pragma unroll
  for (int nt = 0; nt < 4; nt++) biasv[nt] = bias[colb + nt * 16 + lrow];

#pragma unroll
  for (int mf = 0; mf < 8; mf++) {
#pragma unroll
    for (int r = 0; r < 4; r++) {
      const int rowg = bm * 256 + wm * 128 + mf * 16 + lg * 4 + r;
#pragma unroll
      for (int nt = 0; nt < 4; nt++) {
        const int col = colb + nt * 16 + lrow;
        out[(size_t)rowg * 1024 + col] = acc[mf][nt][r] + biasv[nt];
      }
    }
  }
}

// ---------- launch ----------
extern "C" void kernel_launch(void* const* d_in, const int* in_sizes, int n_in,
                              void* d_out, int out_size, void* d_ws, size_t ws_size,
                              hipStream_t stream) {
  const float* x      = (const float*)d_in[0];
  const float* qkv_w  = (const float*)d_in[1];
  const float* qkv_b  = (const float*)d_in[2];
  const float* proj_w = (const float*)d_in[3];
  const float* proj_b = (const float*)d_in[4];
  const float* q_gam  = (const float*)d_in[5];
  const float* k_gam  = (const float*)d_in[6];

  char* ws = (char*)d_ws;
  u16*   xb   = (u16*)(ws);                    // 64 MB (x bf16; later aliased by attn out)
  u16*   qb   = (u16*)(ws + 67108864);         // 64 MB
  u16*   kb   = (u16*)(ws + 134217728);        // 64 MB
  u16*   vb   = (u16*)(ws + 201326592);        // 64 MB  (V^T per head)
  u16*   wqT  = (u16*)(ws + 268435456);        // 6 MB
  u16*   wpT  = (u16*)(ws + 274726912);        // 2 MB
  float* cosT = (float*)(ws + 276824064);      // 256 KB
  float* sinT = (float*)(ws + 277086208);      // 256 KB
  u16*   attn = xb;                            // reuse: x bf16 dead after QKV GEMM

  cvt_bf16<<<32768, 256, 0, stream>>>(x, xb, (size_t)33554432);
  transpose_cvt<<<dim3(48, 16), 256, 0, stream>>>(qkv_w, wqT, 1024, 3072);
  transpose_cvt<<<dim3(16, 16), 256, 0, stream>>>(proj_w, wpT, 1024, 1024);
  rope_tables_kernel<<<1024, 64, 0, stream>>>(cosT, sinT);

  gemm_qkv<<<dim3(1536), dim3(512), 0, stream>>>(xb, wqT, qkv_b, q_gam, k_gam,
                                                 cosT, sinT, qb, kb, vb);
  attn_kernel<<<2048, 256, 0, stream>>>(qb, kb, vb, attn);
  gemm_proj<<<dim3(512), dim3(512), 0, stream>>>(attn, wpT, proj_b, (float*)d_out);
}

// Round 6
// 685.080 us; speedup vs baseline: 1.1047x; 1.0089x over previous
//
#include <hip/hip_runtime.h>
#include <stdint.h>

typedef float f32x4 __attribute__((ext_vector_type(4)));
typedef float f32x16 __attribute__((ext_vector_type(16)));
typedef short s16x8 __attribute__((ext_vector_type(8)));
typedef unsigned short u16;

// ---------- helpers ----------
__device__ __forceinline__ u16 f2bf(float f) {
  union { float f; uint32_t u; } c; c.f = f;
  uint32_t u = c.u;
  u = (u + 0x7fffu + ((u >> 16) & 1u)) >> 16;   // RNE
  return (u16)u;
}

__device__ __forceinline__ void gload16(const void* g, void* lds) {
  __builtin_amdgcn_global_load_lds(
      (const __attribute__((address_space(1))) void*)g,
      (__attribute__((address_space(3))) void*)lds, 16, 0, 0);
}

__device__ __forceinline__ f32x4 mfma16(s16x8 a, s16x8 b, f32x4 c) {
  return __builtin_amdgcn_mfma_f32_16x16x32_bf16(a, b, c, 0, 0, 0);
}

__device__ __forceinline__ f32x16 mfma32(s16x8 a, s16x8 b, f32x16 c) {
  return __builtin_amdgcn_mfma_f32_32x32x16_bf16(a, b, c, 0, 0, 0);
}

// swizzled offset into an unpadded [rows][64] u16 tile: element block (row, c8)
__device__ __forceinline__ int swz(int row, int c8) {
  return row * 64 + ((c8 ^ (row & 7)) << 3);
}

// ---------- small prep kernels ----------
__global__ void cvt_bf16(const float* __restrict__ in, u16* __restrict__ out, size_t n) {
  size_t i = ((size_t)blockIdx.x * blockDim.x + threadIdx.x) * 4;
  if (i < n) {
    float4 v = *(const float4*)&in[i];
    u16 o0 = f2bf(v.x), o1 = f2bf(v.y), o2 = f2bf(v.z), o3 = f2bf(v.w);
    uint2 packed;
    packed.x = (uint32_t)o0 | ((uint32_t)o1 << 16);
    packed.y = (uint32_t)o2 | ((uint32_t)o3 << 16);
    *(uint2*)&out[i] = packed;
  }
}

// tiled transpose: in [rows][cols] fp32 -> out [cols][rows] bf16. grid (cols/64, rows/64)
__global__ void transpose_cvt(const float* __restrict__ in, u16* __restrict__ out,
                              int rows, int cols) {
  __shared__ float tile[64][65];
  const int c0 = blockIdx.x * 64, r0 = blockIdx.y * 64;
  const int tr = threadIdx.x >> 6, tc = threadIdx.x & 63;
#pragma unroll
  for (int i = 0; i < 16; i++) {
    int r = i * 4 + tr;
    tile[r][tc] = in[(size_t)(r0 + r) * cols + c0 + tc];
  }
  __syncthreads();
#pragma unroll
  for (int i = 0; i < 16; i++) {
    int oc = i * 4 + tr;                 // column of `in`
    out[(size_t)(c0 + oc) * rows + r0 + tc] = f2bf(tile[tc][oc]);
  }
}

__global__ void rope_tables_kernel(float* __restrict__ cosT, float* __restrict__ sinT) {
  int n = blockIdx.x;        // 0..1023
  int d = threadIdx.x;       // 0..63
  int ph = n >> 5, pw = n & 31;
  int pos = (d < 32) ? ph : pw;
  int fi = d & 15;
  float freq = powf(10000.f, -(float)fi / 16.f);
  float ang = (float)pos * freq;
  cosT[n * 64 + d] = cosf(ang);
  sinT[n * 64 + d] = sinf(ang);
}

// ============================================================================
// 256x256 8-phase GEMM mainloop (T2 swizzle + T3/T4 counted vmcnt + T5 setprio)
// 512 thr / 8 waves (2M x 4N), BK=64, LDS 128KB dbuf.  (unchanged from R1)
// ============================================================================

#define PH_MID \
  __builtin_amdgcn_sched_barrier(0); \
  __builtin_amdgcn_s_barrier(); \
  asm volatile("s_waitcnt lgkmcnt(0)" ::: "memory"); \
  __builtin_amdgcn_sched_barrier(0); \
  __builtin_amdgcn_s_setprio(1);

#define PH_END \
  __builtin_amdgcn_s_setprio(0); \
  __builtin_amdgcn_sched_barrier(0); \
  __builtin_amdgcn_s_barrier(); \
  __builtin_amdgcn_sched_barrier(0);

#define STAGE(ldsoff, g) do { \
    gload16((g) + (size_t)(w8 + srow) * 1024 + sc8 * 8,       &lds[(ldsoff) + w8 * 64]); \
    gload16((g) + (size_t)(w8 + srow + 64) * 1024 + sc8 * 8,  &lds[(ldsoff) + (w8 + 64) * 64]); \
  } while (0)

#define RD_A(dst, BUF, mh) \
  _Pragma("unroll") \
  for (int mi = 0; mi < 4; mi++) { \
    dst[mi][0] = *(const s16x8*)&lds[(BUF) * 32768 + arow0 + ((mh) * 64 + mi * 16) * 64 + swz0]; \
    dst[mi][1] = *(const s16x8*)&lds[(BUF) * 32768 + arow0 + ((mh) * 64 + mi * 16) * 64 + swz1]; \
  }

#define RD_B(dst, BUF, nh) \
  _Pragma("unroll") \
  for (int ni = 0; ni < 2; ni++) { \
    dst[ni][0] = *(const s16x8*)&lds[(BUF) * 32768 + 16384 + brow0 + ((nh) * 32 + ni * 16) * 64 + swz0]; \
    dst[ni][1] = *(const s16x8*)&lds[(BUF) * 32768 + 16384 + brow0 + ((nh) * 32 + ni * 16) * 64 + swz1]; \
  }

#define MFMA_QUAD(af, bfr, mh, nh) \
  _Pragma("unroll") \
  for (int mi = 0; mi < 4; mi++) \
    _Pragma("unroll") \
    for (int ni = 0; ni < 2; ni++) { \
      acc[(mh) * 4 + mi][(nh) * 2 + ni] = mfma16(af[mi][0], bfr[ni][0], acc[(mh) * 4 + mi][(nh) * 2 + ni]); \
      acc[(mh) * 4 + mi][(nh) * 2 + ni] = mfma16(af[mi][1], bfr[ni][1], acc[(mh) * 4 + mi][(nh) * 2 + ni]); \
    }

// MODE: 0 = steady; 1 = kt==14 (prefetch A only, vmcnt(0)); 2 = kt==15 (no prefetch)
#define KTILE(BUF, KT, MODE) do { \
    s16x8 a0f[4][2], a1f[4][2], b0f[2][2], b1f[2][2]; \
    /* P1 */ \
    RD_A(a0f, BUF, 0); \
    RD_B(b0f, BUF, 0); \
    if ((MODE) < 2) STAGE((1 - (BUF)) * 32768, Ag + (size_t)((KT) + 1) * 64); \
    PH_MID; MFMA_QUAD(a0f, b0f, 0, 0); PH_END; \
    /* P2 */ \
    RD_B(b1f, BUF, 1); \
    if ((MODE) < 2) STAGE((1 - (BUF)) * 32768 + 8192, Ag + (size_t)128 * 1024 + ((KT) + 1) * 64); \
    PH_MID; MFMA_QUAD(a0f, b1f, 0, 1); PH_END; \
    /* P3 */ \
    RD_A(a1f, BUF, 1); \
    if ((MODE) == 0) STAGE((BUF) * 32768 + 16384, Bg + (size_t)((KT) + 2) * 64); \
    PH_MID; MFMA_QUAD(a1f, b1f, 1, 1); PH_END; \
    /* P4 */ \
    if ((MODE) == 0) STAGE((BUF) * 32768 + 16384 + 8192, Bg + (size_t)128 * 1024 + ((KT) + 2) * 64); \
    PH_MID; MFMA_QUAD(a1f, b0f, 1, 0); \
    __builtin_amdgcn_s_setprio(0); \
    if ((MODE) == 0) asm volatile("s_waitcnt vmcnt(4)" ::: "memory"); \
    if ((MODE) == 1) asm volatile("s_waitcnt vmcnt(0)" ::: "memory"); \
    __builtin_amdgcn_sched_barrier(0); \
    __builtin_amdgcn_s_barrier(); \
    __builtin_amdgcn_sched_barrier(0); \
  } while (0)

__device__ __forceinline__ void gemm_mainloop_8ph(
    const u16* __restrict__ Ag, const u16* __restrict__ Bg,
    u16* lds, f32x4 (&acc)[8][4])
{
  const int t = threadIdx.x;
  const int l = t & 63, w = t >> 6;
  const int wm = w & 1, wn = w >> 1;
  const int lrow = l & 15, lg = l >> 4;
  const int srow = l >> 3, sc8 = (l & 7) ^ srow;   // pre-swizzled global chunk
  const int w8 = w * 8;
  const int swz0 = ((0 + lg) ^ (lrow & 7)) << 3;   // kh = 0 (K 0..31)
  const int swz1 = ((4 + lg) ^ (lrow & 7)) << 3;   // kh = 1 (K 32..63)
  const int arow0 = (wm * 128 + lrow) * 64;
  const int brow0 = (wn * 64 + lrow) * 64;

  STAGE(0,                 Ag);
  STAGE(8192,              Ag + (size_t)128 * 1024);
  STAGE(16384,             Bg);
  STAGE(16384 + 8192,      Bg + (size_t)128 * 1024);
  STAGE(32768 + 16384,          Bg + 64);
  STAGE(32768 + 16384 + 8192,   Bg + (size_t)128 * 1024 + 64);
  asm volatile("s_waitcnt vmcnt(4)" ::: "memory");   // kt0 complete; {B0,B1}_1 in flight
  __builtin_amdgcn_sched_barrier(0);
  __builtin_amdgcn_s_barrier();
  __builtin_amdgcn_sched_barrier(0);

#pragma unroll 1
  for (int kt = 0; kt < 14; kt += 2) {
    KTILE(0, kt, 0);
    KTILE(1, kt + 1, 0);
  }
  KTILE(0, 14, 1);
  KTILE(1, 15, 2);
}

// ---------- QKV GEMM + bias + RMSNorm(q,k) + RoPE + q-scale ----------
// q/k written [B*H][N][64]; v written TRANSPOSED per head: [B*H][64][N]
__global__ __launch_bounds__(512, 2) void gemm_qkv(
    const u16* __restrict__ A,   // x bf16 [32768][1024]
    const u16* __restrict__ Bt,  // qkv_w^T bf16 [3072][1024]
    const float* __restrict__ bias,
    const float* __restrict__ qgam, const float* __restrict__ kgam,
    const float* __restrict__ cosT, const float* __restrict__ sinT,
    u16* __restrict__ qb, u16* __restrict__ kb, u16* __restrict__ vb)
{
  __shared__ u16 lds[65536];   // 128 KB
  // XCD-aware bijective swizzle: nwg = 1536 = 8 * 192
  const int bid = blockIdx.x;
  const int sb = (bid & 7) * 192 + (bid >> 3);
  const int bm = sb / 12, bn = sb % 12;

  const f32x4 fzero = {0.f, 0.f, 0.f, 0.f};
  f32x4 acc[8][4];
#pragma unroll
  for (int i = 0; i < 8; i++)
#pragma unroll
    for (int j = 0; j < 4; j++) acc[i][j] = fzero;

  gemm_mainloop_8ph(A + (size_t)bm * 256 * 1024, Bt + (size_t)bn * 256 * 1024, lds, acc);

  const int t = threadIdx.x, l = t & 63, w = t >> 6;
  const int wm = w & 1, wn = w >> 1, lrow = l & 15, lg = l >> 4;
  const int colb = bn * 256 + wn * 64;       // 64-aligned -> single head per wave
  const int s = colb >> 10;                  // 0=q 1=k 2=v
  const int h = (colb & 1023) >> 6;

  float biasv[4];
#pragma unroll
  for (int nt = 0; nt < 4; nt++) biasv[nt] = bias[colb + nt * 16 + lrow];

  if (s < 2) {
    u16* dst = (s == 0) ? qb : kb;
    const float mul = (s == 0) ? 0.18033688011112042f : 1.0f;  // 0.125*log2(e) folded into q
    const float* gamma = (s == 0) ? qgam : kgam;
    float g[4];
#pragma unroll
    for (int nt = 0; nt < 4; nt++) g[nt] = gamma[nt * 16 + lrow] * mul;  // fold q-scale
#pragma unroll
    for (int mf = 0; mf < 8; mf++) {
#pragma unroll
      for (int r = 0; r < 4; r++) {
        const int rowg = bm * 256 + wm * 128 + mf * 16 + lg * 4 + r;
        const int b = rowg >> 10, np = rowg & 1023;
        float tmp[4]; float sq = 0.f;
#pragma unroll
        for (int nt = 0; nt < 4; nt++) {
          float v = acc[mf][nt][r] + biasv[nt];
          tmp[nt] = v; sq += v * v;
        }
#pragma unroll
        for (int off = 1; off < 16; off <<= 1) sq += __shfl_xor(sq, off);
        const float rstd = rsqrtf(sq * 0.015625f + 1e-6f);
#pragma unroll
        for (int nt = 0; nt < 4; nt++) tmp[nt] *= rstd * g[nt];
        const size_t base = (((size_t)(b * 16 + h)) * 1024 + np) * 64;
#pragma unroll
        for (int nt = 0; nt < 4; nt++) {
          const int d = nt * 16 + lrow;
          const float cv = cosT[np * 64 + d], sv = sinT[np * 64 + d];
          const float rh = (nt < 2) ? -tmp[nt + 2] : tmp[nt - 2];
          dst[base + d] = f2bf(tmp[nt] * cv + rh * sv);
        }
      }
    }
  } else {
    // V transposed: vb[(bh*64 + d)*1024 + np]  (R1 epilogue — measured fastest)
#pragma unroll
    for (int mf = 0; mf < 8; mf++) {
#pragma unroll
      for (int r = 0; r < 4; r++) {
        const int rowg = bm * 256 + wm * 128 + mf * 16 + lg * 4 + r;
        const int b = rowg >> 10, np = rowg & 1023;
        const size_t hb = ((size_t)(b * 16 + h)) * 64;
#pragma unroll
        for (int nt = 0; nt < 4; nt++) {
          const int d = nt * 16 + lrow;
          vb[(hb + d) * 1024 + np] = f2bf(acc[mf][nt][r] + biasv[nt]);
        }
      }
    }
  }
}

// ---------- flash attention: 32x32 swapped-QK^T, 64 q-rows/wave ----------
// grid 2048; block 256 = 4 waves, each wave 64 q-rows (2 q-blocks).
// XCD-GROUPED dispatch: 2048 = 8 XCDs x 64 heads x 4 q-tiles. The 4 q-tile
// blocks of a head are consecutive on the SAME XCD -> K/V (256KB/head) is
// fetched from HBM once per head; the other 3 blocks hit that XCD's L2.
// (Default round-robin put them on 4 different XCDs -> 4x K/V HBM traffic.)
// K/V LDS fragments reused across both q-blocks (16 ds_read_b128 : 32 mfma32).
// Q,K row-major per head [1024][64]; V transposed per head [64][1024].
// No running max: |s*scale*log2e| <= 11.5 (RMS-normed q,k), exp2 never overflows.
// S^T = mfma32(K, Q): lane (q=l&31, hi=l>>5) holds P[q][k], k = (r&3)+8*(r>>2)+4*hi.
// PV A-frags assembled IN REGISTERS via v_cvt_pk_bf16_f32 + v_permlane32_swap_b32
// (LO-pair first operand — verified R4).
__global__ __launch_bounds__(256, 2) void attn_kernel(
    const u16* __restrict__ qbuf, const u16* __restrict__ kbuf,
    const u16* __restrict__ vtbuf, u16* __restrict__ obuf)
{
  __shared__ u16 Qs[256 * 64];     // 32KB, xor-swizzled
  __shared__ u16 Ks[2][64 * 64];   // 16KB double-buffered
  __shared__ u16 VTs[2][64 * 64];  // 16KB double-buffered (rows = d, cols = k)
  __shared__ float lsumS[4][2][32];
  const int bx = blockIdx.x;
  // XCD-grouped bijective remap (2048 = 8 * 256; hw assigns XCD = bx & 7)
  const int xcd = bx & 7, idx = bx >> 3;
  const int bh = xcd * 64 + (idx >> 2), qt = idx & 3;
  const int t = threadIdx.x, l = t & 63, w = t >> 6;
  const int q31 = l & 31, hi = l >> 5;

  const u16* qg  = qbuf  + (size_t)bh * 65536 + (size_t)qt * 16384;
  const u16* kg0 = kbuf  + (size_t)bh * 65536;
  const u16* vt0 = vtbuf + (size_t)bh * 65536;

  // staging geometry: lane covers (row r0 + l>>3, swizzled chunk)
  const int srow = l >> 3;
  const int sc8  = (l & 7) ^ (srow & 7);

  // stage Q (256x64)
#pragma unroll
  for (int i = 0; i < 8; i++) {
    const int r0 = (w + i * 4) * 8;
    gload16(qg + (size_t)(r0 + srow) * 64 + sc8 * 8, &Qs[r0 * 64]);
  }
  // stage K,VT tile 0 into buffer 0
#pragma unroll
  for (int i = 0; i < 2; i++) {
    const int r0 = (w + i * 4) * 8;
    gload16(kg0 + (size_t)(r0 + srow) * 64 + sc8 * 8, &Ks[0][r0 * 64]);
    gload16(vt0 + (size_t)(r0 + srow) * 1024 + sc8 * 8, &VTs[0][r0 * 64]);
  }
  asm volatile("s_waitcnt vmcnt(0)" ::: "memory");
  __syncthreads();

  // Q B-frags held in regs whole loop: lane supplies Q[row][ds*16 + hi*8 .. +8]
  s16x8 bq[2][4];
#pragma unroll
  for (int qb = 0; qb < 2; qb++)
#pragma unroll
    for (int ds = 0; ds < 4; ds++)
      bq[qb][ds] = *(const s16x8*)&Qs[swz(w * 64 + qb * 32 + q31, ds * 2 + hi)];

  f32x16 o[2][2];
#pragma unroll
  for (int qb = 0; qb < 2; qb++)
#pragma unroll
    for (int kb2 = 0; kb2 < 2; kb2++)
#pragma unroll
      for (int i = 0; i < 16; i++) o[qb][kb2][i] = 0.f;
  float l_[2] = {0.f, 0.f};

#pragma unroll 2
  for (int kt = 0; kt < 16; kt++) {
    const int cur = kt & 1;
    // issue next tile's stage first: latency hides under this tile's compute
    if (kt < 15) {
      const int kb = (kt + 1) * 64;
#pragma unroll
      for (int i = 0; i < 2; i++) {
        const int r0 = (w + i * 4) * 8;
        gload16(kg0 + (size_t)(kb + r0 + srow) * 64 + sc8 * 8, &Ks[cur ^ 1][r0 * 64]);
        gload16(vt0 + (size_t)(r0 + srow) * 1024 + kb + sc8 * 8, &VTs[cur ^ 1][r0 * 64]);
      }
    }

    // ---- S^T = K Q over d=64: two 32x32 k-blocks x two q-blocks ----
    // K frags loaded once per ds, reused for both q-blocks.
    f32x16 s[2][2];
#pragma unroll
    for (int qb = 0; qb < 2; qb++)
#pragma unroll
      for (int kb2 = 0; kb2 < 2; kb2++)
#pragma unroll
        for (int i = 0; i < 16; i++) s[qb][kb2][i] = 0.f;
    __builtin_amdgcn_s_setprio(1);
#pragma unroll
    for (int ds = 0; ds < 4; ds++) {
      s16x8 ak0 = *(const s16x8*)&Ks[cur][swz(q31, ds * 2 + hi)];
      s16x8 ak1 = *(const s16x8*)&Ks[cur][swz(32 + q31, ds * 2 + hi)];
      s[0][0] = mfma32(ak0, bq[0][ds], s[0][0]);
      s[0][1] = mfma32(ak1, bq[0][ds], s[0][1]);
      s[1][0] = mfma32(ak0, bq[1][ds], s[1][0]);
      s[1][1] = mfma32(ak1, bq[1][ds], s[1][1]);
    }
    __builtin_amdgcn_s_setprio(0);

    // ---- p = exp2(s); lane-local row partial sums; pack PV A-frags ----
    s16x8 pf[2][4];
#pragma unroll
    for (int qb = 0; qb < 2; qb++) {
      float p[32];
#pragma unroll
      for (int r = 0; r < 16; r++) p[r] = __builtin_amdgcn_exp2f(s[qb][0][r]);
#pragma unroll
      for (int r = 0; r < 16; r++) p[16 + r] = __builtin_amdgcn_exp2f(s[qb][1][r]);
      {
        float sm0 = 0.f, sm1 = 0.f, sm2 = 0.f, sm3 = 0.f;
#pragma unroll
        for (int r = 0; r < 8; r++) {
          sm0 += p[r]; sm1 += p[8 + r]; sm2 += p[16 + r]; sm3 += p[24 + r];
        }
        l_[qb] += (sm0 + sm1) + (sm2 + sm3);
      }
      // LO-pair first operand (verified R4): after swap(a1,a2):
      // a1 = [a1_lo; a2_lo] (frag elems 0-1), a2 = [a1_hi; a2_hi] (elems 4-5)
#pragma unroll
      for (int j = 0; j < 4; j++) {
        uint32_t a1, b1, a2, b2;
        asm("v_cvt_pk_bf16_f32 %0, %1, %2" : "=v"(a1) : "v"(p[j * 8 + 0]), "v"(p[j * 8 + 1]));
        asm("v_cvt_pk_bf16_f32 %0, %1, %2" : "=v"(b1) : "v"(p[j * 8 + 2]), "v"(p[j * 8 + 3]));
        asm("v_cvt_pk_bf16_f32 %0, %1, %2" : "=v"(a2) : "v"(p[j * 8 + 4]), "v"(p[j * 8 + 5]));
        asm("v_cvt_pk_bf16_f32 %0, %1, %2" : "=v"(b2) : "v"(p[j * 8 + 6]), "v"(p[j * 8 + 7]));
        asm("v_permlane32_swap_b32 %0, %1" : "+v"(a1), "+v"(a2));
        asm("v_permlane32_swap_b32 %0, %1" : "+v"(b1), "+v"(b2));
        union { s16x8 v; uint32_t u[4]; } cvt;
        cvt.u[0] = a1; cvt.u[1] = b1; cvt.u[2] = a2; cvt.u[3] = b2;
        pf[qb][j] = cvt.v;
      }
    }

    // ---- O += P V : V frags loaded once per j, reused for both q-blocks ----
    __builtin_amdgcn_s_setprio(1);
#pragma unroll
    for (int j = 0; j < 4; j++) {
      s16x8 bv0 = *(const s16x8*)&VTs[cur][swz(q31, j * 2 + hi)];
      s16x8 bv1 = *(const s16x8*)&VTs[cur][swz(32 + q31, j * 2 + hi)];
      o[0][0] = mfma32(pf[0][j], bv0, o[0][0]);
      o[0][1] = mfma32(pf[0][j], bv1, o[0][1]);
      o[1][0] = mfma32(pf[1][j], bv0, o[1][0]);
      o[1][1] = mfma32(pf[1][j], bv1, o[1][1]);
    }
    __builtin_amdgcn_s_setprio(0);

    // one barrier per tile: implicit vmcnt(0)+lgkmcnt(0) drains the stage,
    // and gates buffer reuse for the next iteration.
    __syncthreads();
  }

  // ---- combine row-sum halves (lane ^ 32) via shuffle (alias-safe) ----
#pragma unroll
  for (int qb = 0; qb < 2; qb++) {
    l_[qb] += __shfl_xor(l_[qb], 32);
    if (l < 32) lsumS[w][qb][q31] = 1.0f / l_[qb];
  }

  const int b = bh >> 4, h = bh & 15;
#pragma unroll
  for (int qb = 0; qb < 2; qb++)
#pragma unroll
    for (int r = 0; r < 16; r++) {
      const int q = (r & 3) + 8 * (r >> 2) + 4 * hi;
      const float inv = lsumS[w][qb][q];
      const int n = qt * 256 + w * 64 + qb * 32 + q;
      const size_t base = (((size_t)b * 1024 + n) * 16 + h) * 64;
      obuf[base + q31]      = f2bf(o[qb][0][r] * inv);
      obuf[base + 32 + q31] = f2bf(o[qb][1][r] * inv);
    }
}

// ---------- proj GEMM -> fp32 d_out ----------
__global__ __launch_bounds__(512, 2) void gemm_proj(
    const u16* __restrict__ A,   // attn bf16 [32768][1024]
    const u16* __restrict__ Bt,  // proj_w^T bf16 [1024][1024]
    const float* __restrict__ bias,
    float* __restrict__ out)
{
  __shared__ u16 lds[65536];   // 128 KB
  // XCD-aware bijective swizzle: nwg = 512 = 8 * 64
  const int bid = blockIdx.x;
  const int sb = (bid & 7) * 64 + (bid >> 3);
  const int bm = sb >> 2, bn = sb & 3;

  const f32x4 fzero = {0.f, 0.f, 0.f, 0.f};
  f32x4 acc[8][4];
#pragma unroll
  for (int i = 0; i < 8; i++)
#pragma unroll
    for (int j = 0; j < 4; j++) acc[i][j] = fzero;

  gemm_mainloop_8ph(A + (size_t)bm * 256 * 1024, Bt + (size_t)bn * 256 * 1024, lds, acc);

  const int t = threadIdx.x, l = t & 63, w = t >> 6;
  const int wm = w & 1, wn = w >> 1, lrow = l & 15, lg = l >> 4;
  const int colb = bn * 256 + wn * 64;
  float biasv[4];
#pragma unroll
  for (int nt = 0; nt < 4; nt++) biasv[nt] = bias[colb + nt * 16 + lrow];

#pragma unroll
  for (int mf = 0; mf < 8; mf++) {
#pragma unroll
    for (int r = 0; r < 4; r++) {
      const int rowg = bm * 256 + wm * 128 + mf * 16 + lg * 4 + r;
#pragma unroll
      for (int nt = 0; nt < 4; nt++) {
        const int col = colb + nt * 16 + lrow;
        out[(size_t)rowg * 1024 + col] = acc[mf][nt][r] + biasv[nt];
      }
    }
  }
}

// ---------- launch ----------
extern "C" void kernel_launch(void* const* d_in, const int* in_sizes, int n_in,
                              void* d_out, int out_size, void* d_ws, size_t ws_size,
                              hipStream_t stream) {
  const float* x      = (const float*)d_in[0];
  const float* qkv_w  = (const float*)d_in[1];
  const float* qkv_b  = (const float*)d_in[2];
  const float* proj_w = (const float*)d_in[3];
  const float* proj_b = (const float*)d_in[4];
  const float* q_gam  = (const float*)d_in[5];
  const float* k_gam  = (const float*)d_in[6];

  char* ws = (char*)d_ws;
  u16*   xb   = (u16*)(ws);                    // 64 MB (x bf16; later aliased by attn out)
  u16*   qb   = (u16*)(ws + 67108864);         // 64 MB
  u16*   kb   = (u16*)(ws + 134217728);        // 64 MB
  u16*   vb   = (u16*)(ws + 201326592);        // 64 MB  (V^T per head)
  u16*   wqT  = (u16*)(ws + 268435456);        // 6 MB
  u16*   wpT  = (u16*)(ws + 274726912);        // 2 MB
  float* cosT = (float*)(ws + 276824064);      // 256 KB
  float* sinT = (float*)(ws + 277086208);      // 256 KB
  u16*   attn = xb;                            // reuse: x bf16 dead after QKV GEMM

  cvt_bf16<<<32768, 256, 0, stream>>>(x, xb, (size_t)33554432);
  transpose_cvt<<<dim3(48, 16), 256, 0, stream>>>(qkv_w, wqT, 1024, 3072);
  transpose_cvt<<<dim3(16, 16), 256, 0, stream>>>(proj_w, wpT, 1024, 1024);
  rope_tables_kernel<<<1024, 64, 0, stream>>>(cosT, sinT);

  gemm_qkv<<<dim3(1536), dim3(512), 0, stream>>>(xb, wqT, qkv_b, q_gam, k_gam,
                                                 cosT, sinT, qb, kb, vb);
  attn_kernel<<<2048, 256, 0, stream>>>(qb, kb, vb, attn);
  gemm_proj<<<dim3(512), dim3(512), 0, stream>>>(attn, wpT, proj_b, (float*)d_out);
}